// Round 1
// baseline (1180.071 us; speedup 1.0000x reference)
//
#include <hip/hip_runtime.h>
#include <hip/hip_bf16.h>
#include <math.h>

#define D_MODEL 2048
#define SEQ     2048
#define BATCH   2
#define NTOK    (BATCH*SEQ)      // 4096
#define NHEAD   16
#define HDIM    128
#define FF      8192

typedef float  f32x4  __attribute__((ext_vector_type(4)));
typedef __bf16 bf16x8 __attribute__((ext_vector_type(8)));

__device__ __forceinline__ unsigned short f2bfbits(float f) {
    unsigned u = __builtin_bit_cast(unsigned, f);
    return (unsigned short)((u + 0x7fffu + ((u >> 16) & 1u)) >> 16);
}
__device__ __forceinline__ __bf16 f2bf(float f) {
    unsigned short h = f2bfbits(f);
    return __builtin_bit_cast(__bf16, h);
}

__device__ __forceinline__ void gld_lds16(const void* g, void* l) {
    __builtin_amdgcn_global_load_lds(
        (const __attribute__((address_space(1))) unsigned int*)g,
        (__attribute__((address_space(3))) unsigned int*)l, 16, 0, 0);
}

// ---------------- f32 -> bf16 convert (4 elems/thread) ----------------
__global__ __launch_bounds__(256) void cvt_f32_bf16(
        const float* __restrict__ in, __bf16* __restrict__ out) {
    int i = blockIdx.x * 256 + threadIdx.x;
    float4 v = ((const float4*)in)[i];
    ushort4 o;
    o.x = f2bfbits(v.x); o.y = f2bfbits(v.y);
    o.z = f2bfbits(v.z); o.w = f2bfbits(v.w);
    ((ushort4*)out)[i] = o;
}

// ---------------- LayerNorm: f32 in -> bf16 out, one block per row ----------------
__global__ __launch_bounds__(256) void ln_bf16(
        const float* __restrict__ x, const float* __restrict__ w,
        const float* __restrict__ b, __bf16* __restrict__ out) {
    const int row = blockIdx.x;
    const int tid = threadIdx.x;
    const float* xr = x + (size_t)row * D_MODEL;
    float4 v0 = *(const float4*)(xr + tid * 8);
    float4 v1 = *(const float4*)(xr + tid * 8 + 4);
    float va[8] = {v0.x, v0.y, v0.z, v0.w, v1.x, v1.y, v1.z, v1.w};
    float s = 0.f, ss = 0.f;
#pragma unroll
    for (int j = 0; j < 8; ++j) { s += va[j]; ss += va[j] * va[j]; }
#pragma unroll
    for (int m = 32; m; m >>= 1) { s += __shfl_xor(s, m, 64); ss += __shfl_xor(ss, m, 64); }
    __shared__ float red[8];
    const int wid = tid >> 6;
    if ((tid & 63) == 0) { red[wid * 2] = s; red[wid * 2 + 1] = ss; }
    __syncthreads();
    s  = red[0] + red[2] + red[4] + red[6];
    ss = red[1] + red[3] + red[5] + red[7];
    const float mu   = s * (1.0f / D_MODEL);
    const float var  = ss * (1.0f / D_MODEL) - mu * mu;
    const float rstd = rsqrtf(var + 1e-5f);
    const int c = tid * 8;
    ushort4 o0, o1;
    unsigned short ob[8];
#pragma unroll
    for (int j = 0; j < 8; ++j)
        ob[j] = f2bfbits((va[j] - mu) * rstd * w[c + j] + b[c + j]);
    o0.x = ob[0]; o0.y = ob[1]; o0.z = ob[2]; o0.w = ob[3];
    o1.x = ob[4]; o1.y = ob[5]; o1.z = ob[6]; o1.w = ob[7];
    ushort4* op = (ushort4*)(out + (size_t)row * D_MODEL + c);
    op[0] = o0; op[1] = o1;
}

// ---------------- GEMM: C[M,N] = A[M,K] @ B[N,K]^T  (torch Linear layout) ----------
// 128x128 tile, BK=64, 256 threads (4 waves 2x2, each 64x64 via 4x4 mfma 16x16x32)
// EPI: 0 = bf16 out, 1 = exact-GELU bf16 out, 2 = f32 out with residual add
template <int EPI>
__global__ __launch_bounds__(256) void gemm_bt(
        const __bf16* __restrict__ A, const __bf16* __restrict__ Bm,
        __bf16* __restrict__ Cb, float* __restrict__ Cf,
        const float* __restrict__ resid, int M, int N, int K) {
    __shared__ __align__(16) __bf16 As[128 * 64];
    __shared__ __align__(16) __bf16 Bs[128 * 64];
    const int tid  = threadIdx.x;
    const int wid  = tid >> 6, lane = tid & 63;
    const int l16  = lane & 15, lhi = lane >> 4;   // lhi in 0..3
    const int wr   = wid >> 1,  wc  = wid & 1;
    const int bm   = blockIdx.y, bn = blockIdx.x;
    const __bf16* Abase = A  + (size_t)bm * 128 * K;
    const __bf16* Bbase = Bm + (size_t)bn * 128 * K;
    f32x4 acc[4][4] = {};

    for (int k0 = 0; k0 < K; k0 += 64) {
#pragma unroll
        for (int i = 0; i < 4; ++i) {
            int idx = i * 256 + tid;
            int row = idx >> 3, col = (idx & 7) * 8;
            gld_lds16(Abase + (size_t)row * K + k0 + col, As + idx * 8);
            gld_lds16(Bbase + (size_t)row * K + k0 + col, Bs + idx * 8);
        }
        __syncthreads();   // drains vmcnt -> staging visible
#pragma unroll
        for (int ks = 0; ks < 2; ++ks) {
            bf16x8 af[4], bfr[4];
#pragma unroll
            for (int m = 0; m < 4; ++m)
                af[m] = *(const bf16x8*)(As + (wr * 64 + m * 16 + l16) * 64 + ks * 32 + lhi * 8);
#pragma unroll
            for (int n = 0; n < 4; ++n)
                bfr[n] = *(const bf16x8*)(Bs + (wc * 64 + n * 16 + l16) * 64 + ks * 32 + lhi * 8);
#pragma unroll
            for (int m = 0; m < 4; ++m)
#pragma unroll
                for (int n = 0; n < 4; ++n)
                    acc[m][n] = __builtin_amdgcn_mfma_f32_16x16x32_bf16(af[m], bfr[n], acc[m][n], 0, 0, 0);
        }
        __syncthreads();   // all waves done reading before next stage
    }

#pragma unroll
    for (int m = 0; m < 4; ++m) {
        const int row = bm * 128 + wr * 64 + m * 16 + lhi * 4;
#pragma unroll
        for (int n = 0; n < 4; ++n) {
            const int col = bn * 128 + wc * 64 + n * 16 + l16;
#pragma unroll
            for (int r = 0; r < 4; ++r) {
                float v = acc[m][n][r];
                size_t off = (size_t)(row + r) * N + col;
                if (EPI == 0) {
                    Cb[off] = f2bf(v);
                } else if (EPI == 1) {
                    Cb[off] = f2bf(0.5f * v * (1.0f + erff(v * 0.70710678118654752f)));
                } else {
                    Cf[off] = v + resid[off];
                }
            }
        }
    }
}

// ---------------- Causal flash attention ----------------
// grid: (S/64, NHEAD, BATCH), 256 threads. Wave w owns Q rows [qt*64+w*16, +16).
// K staged via global_load_lds with XOR-swizzled SOURCE (rule #21); V transposed
// into padded LDS; per-wave P relayout through LDS; online softmax.
__global__ __launch_bounds__(256) void attn_causal(
        const __bf16* __restrict__ Q, const __bf16* __restrict__ K,
        const __bf16* __restrict__ V, __bf16* __restrict__ O) {
    const int qt = blockIdx.x, h = blockIdx.y, bb = blockIdx.z;
    const int tid = threadIdx.x, wid = tid >> 6, lane = tid & 63;
    const int l16 = lane & 15, lhi = lane >> 4;
    __shared__ __align__(16) __bf16 Ks[64 * 128];      // linear dest, xor-swizzled content
    __shared__ __align__(16) __bf16 Vt[128 * 72];      // [d][tok], pad 72
    __shared__ __align__(16) __bf16 Pl[4][16 * 72];    // per-wave P [q][tok], pad 72

    const size_t base = ((size_t)bb * SEQ) * D_MODEL + (size_t)h * HDIM;
    const int q0 = qt * 64 + wid * 16;

    bf16x8 qf[4];
#pragma unroll
    for (int ks = 0; ks < 4; ++ks)
        qf[ks] = *(const bf16x8*)(Q + base + (size_t)(q0 + l16) * D_MODEL + ks * 32 + lhi * 8);

    f32x4 accO[8] = {};
    float m_run[4], l_run[4];
#pragma unroll
    for (int r = 0; r < 4; ++r) { m_run[r] = -1e30f; l_run[r] = 0.f; }

    for (int kt = 0; kt <= qt; ++kt) {
        // stage K (source-swizzled so swizzled reads are conflict-free)
#pragma unroll
        for (int i = 0; i < 4; ++i) {
            int idx = i * 256 + tid;
            int row = idx >> 4, c8 = idx & 15;
            int c8s = c8 ^ (row & 7);
            gld_lds16(K + base + (size_t)(kt * 64 + row) * D_MODEL + c8s * 8, Ks + idx * 8);
        }
        // stage V transposed (reg path, scalar LDS writes)
#pragma unroll
        for (int i = 0; i < 4; ++i) {
            int idx = i * 256 + tid;
            int row = idx >> 4, c8 = idx & 15;
            bf16x8 v = *(const bf16x8*)(V + base + (size_t)(kt * 64 + row) * D_MODEL + c8 * 8);
#pragma unroll
            for (int j = 0; j < 8; ++j)
                Vt[(c8 * 8 + j) * 72 + row] = v[j];
        }
        __syncthreads();

        // QK^T : s[nb] covers toks nb*16+l16, rows lhi*4+r
        f32x4 s[4] = {};
#pragma unroll
        for (int nb = 0; nb < 4; ++nb) {
            const int tok = nb * 16 + l16;
#pragma unroll
            for (int ks = 0; ks < 4; ++ks) {
                int co = (ks * 64 + lhi * 16) ^ ((tok & 7) << 4);
                bf16x8 kf = *(const bf16x8*)((const char*)Ks + tok * 256 + co);
                s[nb] = __builtin_amdgcn_mfma_f32_16x16x32_bf16(qf[ks], kf, s[nb], 0, 0, 0);
            }
        }
        const float scale = 0.08838834764831845f;  // 1/sqrt(128)
        const bool diag = (kt == qt);
#pragma unroll
        for (int nb = 0; nb < 4; ++nb)
#pragma unroll
            for (int r = 0; r < 4; ++r) {
                float sv = s[nb][r] * scale;
                if (diag && (nb * 16 + l16) > (wid * 16 + lhi * 4 + r)) sv = -1e30f;
                s[nb][r] = sv;
            }
        float alpha[4];
#pragma unroll
        for (int r = 0; r < 4; ++r) {
            float mx = fmaxf(fmaxf(s[0][r], s[1][r]), fmaxf(s[2][r], s[3][r]));
#pragma unroll
            for (int m = 8; m; m >>= 1) mx = fmaxf(mx, __shfl_xor(mx, m, 64));
            float mnew = fmaxf(m_run[r], mx);
            alpha[r] = __expf(m_run[r] - mnew);
            float rs = 0.f;
#pragma unroll
            for (int nb = 0; nb < 4; ++nb) {
                float p = __expf(s[nb][r] - mnew);
                s[nb][r] = p;
                rs += p;
            }
#pragma unroll
            for (int m = 8; m; m >>= 1) rs += __shfl_xor(rs, m, 64);
            l_run[r] = l_run[r] * alpha[r] + rs;
            m_run[r] = mnew;
        }
#pragma unroll
        for (int d8 = 0; d8 < 8; ++d8)
#pragma unroll
            for (int r = 0; r < 4; ++r) accO[d8][r] *= alpha[r];
        // P -> LDS in A-fragment layout [q][tok]
#pragma unroll
        for (int nb = 0; nb < 4; ++nb)
#pragma unroll
            for (int r = 0; r < 4; ++r)
                Pl[wid][(lhi * 4 + r) * 72 + nb * 16 + l16] = f2bf(s[nb][r]);
        // PV
#pragma unroll
        for (int ks2 = 0; ks2 < 2; ++ks2) {
            bf16x8 pa = *(const bf16x8*)(&Pl[wid][l16 * 72 + ks2 * 32 + lhi * 8]);
#pragma unroll
            for (int d8 = 0; d8 < 8; ++d8) {
                bf16x8 vf = *(const bf16x8*)(Vt + (d8 * 16 + l16) * 72 + ks2 * 32 + lhi * 8);
                accO[d8] = __builtin_amdgcn_mfma_f32_16x16x32_bf16(pa, vf, accO[d8], 0, 0, 0);
            }
        }
        __syncthreads();
    }

#pragma unroll
    for (int d8 = 0; d8 < 8; ++d8)
#pragma unroll
        for (int r = 0; r < 4; ++r) {
            float o = accO[d8][r] / l_run[r];
            O[base + (size_t)(q0 + lhi * 4 + r) * D_MODEL + d8 * 16 + l16] = f2bf(o);
        }
}

// ---------------- host launcher ----------------
extern "C" void kernel_launch(void* const* d_in, const int* in_sizes, int n_in,
                              void* d_out, int out_size, void* d_ws, size_t ws_size,
                              hipStream_t stream) {
    const float* x    = (const float*)d_in[0];
    const float* tok  = (const float*)d_in[1];
    const float* Wq   = (const float*)d_in[2];
    const float* Wk   = (const float*)d_in[3];
    const float* Wv   = (const float*)d_in[4];
    const float* Wo   = (const float*)d_in[5];
    const float* W1   = (const float*)d_in[6];
    const float* W2   = (const float*)d_in[7];
    const float* ln1w = (const float*)d_in[8];
    const float* ln1b = (const float*)d_in[9];
    const float* ln2w = (const float*)d_in[10];
    const float* ln2b = (const float*)d_in[11];
    float* out = (float*)d_out;

    char* ws = (char*)d_ws;
    size_t off = 0;
    auto alloc = [&](size_t bytes) { void* p = ws + off; off += bytes; return p; };
    __bf16* tokb  = (__bf16*)alloc((size_t)NTOK * D_MODEL * 2);       // 16 MB
    __bf16* hnorm = (__bf16*)alloc((size_t)NTOK * D_MODEL * 2);       // 16 MB (reused as h2)
    __bf16* wqb   = (__bf16*)alloc((size_t)D_MODEL * D_MODEL * 2);
    __bf16* wkb   = (__bf16*)alloc((size_t)D_MODEL * D_MODEL * 2);
    __bf16* wvb   = (__bf16*)alloc((size_t)D_MODEL * D_MODEL * 2);
    __bf16* wob   = (__bf16*)alloc((size_t)D_MODEL * D_MODEL * 2);
    __bf16* w1b   = (__bf16*)alloc((size_t)FF * D_MODEL * 2);
    __bf16* w2b   = (__bf16*)alloc((size_t)D_MODEL * FF * 2);
    __bf16* Qb    = (__bf16*)alloc((size_t)NTOK * D_MODEL * 2);
    __bf16* Kb    = (__bf16*)alloc((size_t)NTOK * D_MODEL * 2);
    __bf16* Vb    = (__bf16*)alloc((size_t)NTOK * D_MODEL * 2);
    __bf16* Ab    = (__bf16*)alloc((size_t)NTOK * D_MODEL * 2);
    __bf16* gb    = Qb;  // GEMM1 output aliases Q/K/V/attn block (dead by then)
    float*  x2    = (float*)alloc((size_t)NTOK * D_MODEL * 4);        // 32 MB

    // converts
    cvt_f32_bf16<<<(NTOK * D_MODEL) / 1024, 256, 0, stream>>>(tok, tokb);
    cvt_f32_bf16<<<(D_MODEL * D_MODEL) / 1024, 256, 0, stream>>>(Wq, wqb);
    cvt_f32_bf16<<<(D_MODEL * D_MODEL) / 1024, 256, 0, stream>>>(Wk, wkb);
    cvt_f32_bf16<<<(D_MODEL * D_MODEL) / 1024, 256, 0, stream>>>(Wv, wvb);
    cvt_f32_bf16<<<(D_MODEL * D_MODEL) / 1024, 256, 0, stream>>>(Wo, wob);
    cvt_f32_bf16<<<(FF * D_MODEL) / 1024, 256, 0, stream>>>(W1, w1b);
    cvt_f32_bf16<<<(FF * D_MODEL) / 1024, 256, 0, stream>>>(W2, w2b);

    ln_bf16<<<NTOK, 256, 0, stream>>>(x, ln1w, ln1b, hnorm);

    dim3 gsq(D_MODEL / 128, NTOK / 128);   // (16, 32)
    gemm_bt<0><<<gsq, 256, 0, stream>>>(hnorm, wqb, Qb, nullptr, nullptr, NTOK, D_MODEL, D_MODEL);
    gemm_bt<0><<<gsq, 256, 0, stream>>>(hnorm, wkb, Kb, nullptr, nullptr, NTOK, D_MODEL, D_MODEL);
    gemm_bt<0><<<gsq, 256, 0, stream>>>(tokb, wvb, Vb, nullptr, nullptr, NTOK, D_MODEL, D_MODEL);

    attn_causal<<<dim3(SEQ / 64, NHEAD, BATCH), 256, 0, stream>>>(Qb, Kb, Vb, Ab);

    gemm_bt<2><<<gsq, 256, 0, stream>>>(Ab, wob, nullptr, x2, x, NTOK, D_MODEL, D_MODEL);

    ln_bf16<<<NTOK, 256, 0, stream>>>(x2, ln2w, ln2b, hnorm);   // h2

    dim3 gff(FF / 128, NTOK / 128);        // (64, 32)
    gemm_bt<1><<<gff, 256, 0, stream>>>(hnorm, w1b, gb, nullptr, nullptr, NTOK, FF, D_MODEL);
    gemm_bt<2><<<gsq, 256, 0, stream>>>(gb, w2b, nullptr, out, x2, NTOK, D_MODEL, FF);
}

// Round 2
// 982.961 us; speedup vs baseline: 1.2005x; 1.2005x over previous
//
#include <hip/hip_runtime.h>
#include <hip/hip_bf16.h>
#include <math.h>

#define D_MODEL 2048
#define SEQ     2048
#define BATCH   2
#define NTOK    (BATCH*SEQ)      // 4096
#define NHEAD   16
#define HDIM    128
#define FF      8192

typedef float  f32x4  __attribute__((ext_vector_type(4)));
typedef __bf16 bf16x8 __attribute__((ext_vector_type(8)));

__device__ __forceinline__ unsigned short f2bfbits(float f) {
    unsigned u = __builtin_bit_cast(unsigned, f);
    return (unsigned short)((u + 0x7fffu + ((u >> 16) & 1u)) >> 16);
}
__device__ __forceinline__ __bf16 f2bf(float f) {
    unsigned short h = f2bfbits(f);
    return __builtin_bit_cast(__bf16, h);
}

__device__ __forceinline__ void gld_lds16(const void* g, void* l) {
    __builtin_amdgcn_global_load_lds(
        (const __attribute__((address_space(1))) unsigned int*)g,
        (__attribute__((address_space(3))) unsigned int*)l, 16, 0, 0);
}

// ---------------- f32 -> bf16 convert (4 elems/thread) ----------------
__global__ __launch_bounds__(256) void cvt_f32_bf16(
        const float* __restrict__ in, __bf16* __restrict__ out) {
    int i = blockIdx.x * 256 + threadIdx.x;
    float4 v = ((const float4*)in)[i];
    ushort4 o;
    o.x = f2bfbits(v.x); o.y = f2bfbits(v.y);
    o.z = f2bfbits(v.z); o.w = f2bfbits(v.w);
    ((ushort4*)out)[i] = o;
}

// ---------------- LayerNorm: f32 in -> bf16 out, one block per row ----------------
__global__ __launch_bounds__(256) void ln_bf16(
        const float* __restrict__ x, const float* __restrict__ w,
        const float* __restrict__ b, __bf16* __restrict__ out) {
    const int row = blockIdx.x;
    const int tid = threadIdx.x;
    const float* xr = x + (size_t)row * D_MODEL;
    float4 v0 = *(const float4*)(xr + tid * 8);
    float4 v1 = *(const float4*)(xr + tid * 8 + 4);
    float va[8] = {v0.x, v0.y, v0.z, v0.w, v1.x, v1.y, v1.z, v1.w};
    float s = 0.f, ss = 0.f;
#pragma unroll
    for (int j = 0; j < 8; ++j) { s += va[j]; ss += va[j] * va[j]; }
#pragma unroll
    for (int m = 32; m; m >>= 1) { s += __shfl_xor(s, m, 64); ss += __shfl_xor(ss, m, 64); }
    __shared__ float red[8];
    const int wid = tid >> 6;
    if ((tid & 63) == 0) { red[wid * 2] = s; red[wid * 2 + 1] = ss; }
    __syncthreads();
    s  = red[0] + red[2] + red[4] + red[6];
    ss = red[1] + red[3] + red[5] + red[7];
    const float mu   = s * (1.0f / D_MODEL);
    const float var  = ss * (1.0f / D_MODEL) - mu * mu;
    const float rstd = rsqrtf(var + 1e-5f);
    const int c = tid * 8;
    ushort4 o0, o1;
    unsigned short ob[8];
#pragma unroll
    for (int j = 0; j < 8; ++j)
        ob[j] = f2bfbits((va[j] - mu) * rstd * w[c + j] + b[c + j]);
    o0.x = ob[0]; o0.y = ob[1]; o0.z = ob[2]; o0.w = ob[3];
    o1.x = ob[4]; o1.y = ob[5]; o1.z = ob[6]; o1.w = ob[7];
    ushort4* op = (ushort4*)(out + (size_t)row * D_MODEL + c);
    op[0] = o0; op[1] = o1;
}

// ---------------- GEMM: C[M,N] = A[M,K] @ B[N,K]^T  (torch Linear layout) ----------
// 128x128 tile, BK=64, 256 threads (4 waves 2x2, each 64x64 via 4x4 mfma 16x16x32)
// EPI: 0 = bf16 out, 1 = exact-GELU bf16 out, 2 = f32 out with residual add,
//      3 = bf16 out transposed to [b, h, hd, s] (for attention V operand)
template <int EPI>
__global__ __launch_bounds__(256) void gemm_bt(
        const __bf16* __restrict__ A, const __bf16* __restrict__ Bm,
        __bf16* __restrict__ Cb, float* __restrict__ Cf,
        const float* __restrict__ resid, int M, int N, int K) {
    __shared__ __align__(16) __bf16 As[128 * 64];
    __shared__ __align__(16) __bf16 Bs[128 * 64];
    const int tid  = threadIdx.x;
    const int wid  = tid >> 6, lane = tid & 63;
    const int l16  = lane & 15, lhi = lane >> 4;   // lhi in 0..3
    const int wr   = wid >> 1,  wc  = wid & 1;
    const int bm   = blockIdx.y, bn = blockIdx.x;
    const __bf16* Abase = A  + (size_t)bm * 128 * K;
    const __bf16* Bbase = Bm + (size_t)bn * 128 * K;
    f32x4 acc[4][4] = {};

    for (int k0 = 0; k0 < K; k0 += 64) {
#pragma unroll
        for (int i = 0; i < 4; ++i) {
            int idx = i * 256 + tid;
            int row = idx >> 3, col = (idx & 7) * 8;
            gld_lds16(Abase + (size_t)row * K + k0 + col, As + idx * 8);
            gld_lds16(Bbase + (size_t)row * K + k0 + col, Bs + idx * 8);
        }
        __syncthreads();   // drains vmcnt -> staging visible
#pragma unroll
        for (int ks = 0; ks < 2; ++ks) {
            bf16x8 af[4], bfr[4];
#pragma unroll
            for (int m = 0; m < 4; ++m)
                af[m] = *(const bf16x8*)(As + (wr * 64 + m * 16 + l16) * 64 + ks * 32 + lhi * 8);
#pragma unroll
            for (int n = 0; n < 4; ++n)
                bfr[n] = *(const bf16x8*)(Bs + (wc * 64 + n * 16 + l16) * 64 + ks * 32 + lhi * 8);
#pragma unroll
            for (int m = 0; m < 4; ++m)
#pragma unroll
                for (int n = 0; n < 4; ++n)
                    acc[m][n] = __builtin_amdgcn_mfma_f32_16x16x32_bf16(af[m], bfr[n], acc[m][n], 0, 0, 0);
        }
        __syncthreads();   // all waves done reading before next stage
    }

#pragma unroll
    for (int m = 0; m < 4; ++m) {
        const int row = bm * 128 + wr * 64 + m * 16 + lhi * 4;
#pragma unroll
        for (int n = 0; n < 4; ++n) {
            const int col = bn * 128 + wc * 64 + n * 16 + l16;
            if (EPI == 3) {
                // transposed store: element (s=row+r, d=col) -> Vt[b][h][hd][s]
                // 4 r's are 4 consecutive s at fixed d -> one ushort4 store
                const int h = col >> 7, hd = col & 127;
                const size_t obase =
                    ((((size_t)(row >> 11) * NHEAD + h) * HDIM + hd) << 11) + (row & 2047);
                ushort4 o;
                o.x = f2bfbits(acc[m][n][0]); o.y = f2bfbits(acc[m][n][1]);
                o.z = f2bfbits(acc[m][n][2]); o.w = f2bfbits(acc[m][n][3]);
                *(ushort4*)((unsigned short*)Cb + obase) = o;
            } else {
#pragma unroll
                for (int r = 0; r < 4; ++r) {
                    float v = acc[m][n][r];
                    size_t off = (size_t)(row + r) * N + col;
                    if (EPI == 0) {
                        Cb[off] = f2bf(v);
                    } else if (EPI == 1) {
                        Cb[off] = f2bf(0.5f * v * (1.0f + erff(v * 0.70710678118654752f)));
                    } else {
                        Cf[off] = v + resid[off];
                    }
                }
            }
        }
    }
}

// ---------------- Causal flash attention ----------------
// grid: (S/64, NHEAD, BATCH), 256 threads. Wave w owns Q rows [qt*64+w*16, +16).
// qt remapped heavy-first for causal load balance. K staged via global_load_lds
// with XOR-swizzled SOURCE (rule #21: inverse-swz source + swz read). V comes in
// pre-transposed [b,h,d,s] from the V-projection GEMM and is staged the same way
// (no in-kernel transpose, no scalar LDS writes). Online softmax in base-2.
__global__ __launch_bounds__(256) void attn_causal(
        const __bf16* __restrict__ Q, const __bf16* __restrict__ K,
        const __bf16* __restrict__ Vt, __bf16* __restrict__ O) {
    const int qt = gridDim.x - 1 - blockIdx.x;   // heavy blocks first
    const int h = blockIdx.y, bb = blockIdx.z;
    const int tid = threadIdx.x, wid = tid >> 6, lane = tid & 63;
    const int l16 = lane & 15, lhi = lane >> 4;
    __shared__ __align__(16) __bf16 Ks[64 * 128];   // [tok][d], chunk-swizzled
    __shared__ __align__(16) __bf16 Vs[128 * 64];   // [d][tok], chunk-swizzled
    __shared__ __align__(16) __bf16 Pl[4][16 * 72]; // per-wave P [q][tok], pad 72

    const size_t base   = ((size_t)bb * SEQ) * D_MODEL + (size_t)h * HDIM;
    const size_t vtbase = (((size_t)bb * NHEAD + h) * HDIM) << 11;  // [d][s], row=2048
    const int q0 = qt * 64 + wid * 16;

    bf16x8 qf[4];
#pragma unroll
    for (int ks = 0; ks < 4; ++ks)
        qf[ks] = *(const bf16x8*)(Q + base + (size_t)(q0 + l16) * D_MODEL + ks * 32 + lhi * 8);

    f32x4 accO[8] = {};
    float m_run[4], l_run[4];
#pragma unroll
    for (int r = 0; r < 4; ++r) { m_run[r] = -1e30f; l_run[r] = 0.f; }

    // 1/sqrt(128) * log2(e): softmax carried in base-2 domain
    const float scale2 = 0.08838834764831845f * 1.4426950408889634f;

    for (int kt = 0; kt <= qt; ++kt) {
        // stage K [64 tok][16 chunks], source pre-swizzled -> swizzled reads conflict-free
#pragma unroll
        for (int i = 0; i < 4; ++i) {
            int idx = i * 256 + tid;
            int row = idx >> 4, c8 = idx & 15;
            int c8s = c8 ^ (row & 7);
            gld_lds16(K + base + (size_t)(kt * 64 + row) * D_MODEL + c8s * 8, Ks + idx * 8);
        }
        // stage V^T [128 d][8 chunks of 8 tok], same swizzle scheme
#pragma unroll
        for (int i = 0; i < 4; ++i) {
            int idx = i * 256 + tid;
            int row = idx >> 3, c8 = idx & 7;
            int c8s = c8 ^ (row & 7);
            gld_lds16(Vt + vtbase + (size_t)row * SEQ + kt * 64 + c8s * 8, Vs + idx * 8);
        }
        __syncthreads();

        // QK^T : s[nb] covers toks nb*16+l16, rows lhi*4+r
        f32x4 s[4] = {};
        __builtin_amdgcn_s_setprio(1);
#pragma unroll
        for (int nb = 0; nb < 4; ++nb) {
            const int tok = nb * 16 + l16;
#pragma unroll
            for (int ks = 0; ks < 4; ++ks) {
                int co = (ks * 64 + lhi * 16) ^ ((tok & 7) << 4);
                bf16x8 kf = *(const bf16x8*)((const char*)Ks + tok * 256 + co);
                s[nb] = __builtin_amdgcn_mfma_f32_16x16x32_bf16(qf[ks], kf, s[nb], 0, 0, 0);
            }
        }
        __builtin_amdgcn_s_setprio(0);
        const bool diag = (kt == qt);
#pragma unroll
        for (int nb = 0; nb < 4; ++nb)
#pragma unroll
            for (int r = 0; r < 4; ++r) {
                float sv = s[nb][r] * scale2;
                if (diag && (nb * 16 + l16) > (wid * 16 + lhi * 4 + r)) sv = -1e30f;
                s[nb][r] = sv;
            }
        float alpha[4];
#pragma unroll
        for (int r = 0; r < 4; ++r) {
            float mx = fmaxf(fmaxf(s[0][r], s[1][r]), fmaxf(s[2][r], s[3][r]));
#pragma unroll
            for (int m = 8; m; m >>= 1) mx = fmaxf(mx, __shfl_xor(mx, m, 64));
            float mnew = fmaxf(m_run[r], mx);
            alpha[r] = exp2f(m_run[r] - mnew);
            float rs = 0.f;
#pragma unroll
            for (int nb = 0; nb < 4; ++nb) {
                float p = exp2f(s[nb][r] - mnew);
                s[nb][r] = p;
                rs += p;
            }
#pragma unroll
            for (int m = 8; m; m >>= 1) rs += __shfl_xor(rs, m, 64);
            l_run[r] = l_run[r] * alpha[r] + rs;
            m_run[r] = mnew;
        }
#pragma unroll
        for (int d8 = 0; d8 < 8; ++d8)
#pragma unroll
            for (int r = 0; r < 4; ++r) accO[d8][r] *= alpha[r];
        // P -> LDS in A-fragment layout [q][tok]
#pragma unroll
        for (int nb = 0; nb < 4; ++nb)
#pragma unroll
            for (int r = 0; r < 4; ++r)
                Pl[wid][(lhi * 4 + r) * 72 + nb * 16 + l16] = f2bf(s[nb][r]);
        // PV: vf = V^T[d = d8*16+l16][tok chunk (ks2*4+lhi) ^ (d&7)]
        __builtin_amdgcn_s_setprio(1);
#pragma unroll
        for (int ks2 = 0; ks2 < 2; ++ks2) {
            bf16x8 pa = *(const bf16x8*)(&Pl[wid][l16 * 72 + ks2 * 32 + lhi * 8]);
#pragma unroll
            for (int d8 = 0; d8 < 8; ++d8) {
                const int d = d8 * 16 + l16;
                const int co = ((ks2 * 4 + lhi) ^ (d & 7)) << 4;
                bf16x8 vf = *(const bf16x8*)((const char*)Vs + d * 128 + co);
                accO[d8] = __builtin_amdgcn_mfma_f32_16x16x32_bf16(pa, vf, accO[d8], 0, 0, 0);
            }
        }
        __builtin_amdgcn_s_setprio(0);
        __syncthreads();
    }

    const float ln2 = 0.69314718055994531f;
    (void)ln2;
#pragma unroll
    for (int d8 = 0; d8 < 8; ++d8)
#pragma unroll
        for (int r = 0; r < 4; ++r) {
            float o = accO[d8][r] / l_run[r];
            O[base + (size_t)(q0 + lhi * 4 + r) * D_MODEL + d8 * 16 + l16] = f2bf(o);
        }
}

// ---------------- host launcher ----------------
extern "C" void kernel_launch(void* const* d_in, const int* in_sizes, int n_in,
                              void* d_out, int out_size, void* d_ws, size_t ws_size,
                              hipStream_t stream) {
    const float* x    = (const float*)d_in[0];
    const float* tok  = (const float*)d_in[1];
    const float* Wq   = (const float*)d_in[2];
    const float* Wk   = (const float*)d_in[3];
    const float* Wv   = (const float*)d_in[4];
    const float* Wo   = (const float*)d_in[5];
    const float* W1   = (const float*)d_in[6];
    const float* W2   = (const float*)d_in[7];
    const float* ln1w = (const float*)d_in[8];
    const float* ln1b = (const float*)d_in[9];
    const float* ln2w = (const float*)d_in[10];
    const float* ln2b = (const float*)d_in[11];
    float* out = (float*)d_out;

    char* ws = (char*)d_ws;
    size_t off = 0;
    auto alloc = [&](size_t bytes) { void* p = ws + off; off += bytes; return p; };
    __bf16* tokb  = (__bf16*)alloc((size_t)NTOK * D_MODEL * 2);       // 16 MB
    __bf16* hnorm = (__bf16*)alloc((size_t)NTOK * D_MODEL * 2);       // 16 MB (reused as h2)
    __bf16* wqb   = (__bf16*)alloc((size_t)D_MODEL * D_MODEL * 2);
    __bf16* wkb   = (__bf16*)alloc((size_t)D_MODEL * D_MODEL * 2);
    __bf16* wvb   = (__bf16*)alloc((size_t)D_MODEL * D_MODEL * 2);
    __bf16* wob   = (__bf16*)alloc((size_t)D_MODEL * D_MODEL * 2);
    __bf16* w1b   = (__bf16*)alloc((size_t)FF * D_MODEL * 2);
    __bf16* w2b   = (__bf16*)alloc((size_t)D_MODEL * FF * 2);
    __bf16* Qb    = (__bf16*)alloc((size_t)NTOK * D_MODEL * 2);
    __bf16* Kb    = (__bf16*)alloc((size_t)NTOK * D_MODEL * 2);
    __bf16* Vtg   = (__bf16*)alloc((size_t)NTOK * D_MODEL * 2);       // V^T [b,h,d,s]
    __bf16* Ab    = (__bf16*)alloc((size_t)NTOK * D_MODEL * 2);
    __bf16* gb    = Qb;  // FFN intermediate aliases Qb..Ab (64 MB, all dead by then)
    float*  x2    = (float*)alloc((size_t)NTOK * D_MODEL * 4);        // 32 MB

    // converts
    cvt_f32_bf16<<<(NTOK * D_MODEL) / 1024, 256, 0, stream>>>(tok, tokb);
    cvt_f32_bf16<<<(D_MODEL * D_MODEL) / 1024, 256, 0, stream>>>(Wq, wqb);
    cvt_f32_bf16<<<(D_MODEL * D_MODEL) / 1024, 256, 0, stream>>>(Wk, wkb);
    cvt_f32_bf16<<<(D_MODEL * D_MODEL) / 1024, 256, 0, stream>>>(Wv, wvb);
    cvt_f32_bf16<<<(D_MODEL * D_MODEL) / 1024, 256, 0, stream>>>(Wo, wob);
    cvt_f32_bf16<<<(FF * D_MODEL) / 1024, 256, 0, stream>>>(W1, w1b);
    cvt_f32_bf16<<<(FF * D_MODEL) / 1024, 256, 0, stream>>>(W2, w2b);

    ln_bf16<<<NTOK, 256, 0, stream>>>(x, ln1w, ln1b, hnorm);

    dim3 gsq(D_MODEL / 128, NTOK / 128);   // (16, 32)
    gemm_bt<0><<<gsq, 256, 0, stream>>>(hnorm, wqb, Qb, nullptr, nullptr, NTOK, D_MODEL, D_MODEL);
    gemm_bt<0><<<gsq, 256, 0, stream>>>(hnorm, wkb, Kb, nullptr, nullptr, NTOK, D_MODEL, D_MODEL);
    gemm_bt<3><<<gsq, 256, 0, stream>>>(tokb, wvb, Vtg, nullptr, nullptr, NTOK, D_MODEL, D_MODEL);

    attn_causal<<<dim3(SEQ / 64, NHEAD, BATCH), 256, 0, stream>>>(Qb, Kb, Vtg, Ab);

    gemm_bt<2><<<gsq, 256, 0, stream>>>(Ab, wob, nullptr, x2, x, NTOK, D_MODEL, D_MODEL);

    ln_bf16<<<NTOK, 256, 0, stream>>>(x2, ln2w, ln2b, hnorm);   // h2

    dim3 gff(FF / 128, NTOK / 128);        // (64, 32)
    gemm_bt<1><<<gff, 256, 0, stream>>>(hnorm, w1b, gb, nullptr, nullptr, NTOK, FF, D_MODEL);
    gemm_bt<2><<<gsq, 256, 0, stream>>>(gb, w2b, nullptr, out, x2, NTOK, D_MODEL, FF);
}

// Round 3
// 960.147 us; speedup vs baseline: 1.2291x; 1.0238x over previous
//
#include <hip/hip_runtime.h>
#include <hip/hip_bf16.h>
#include <math.h>

#define D_MODEL 2048
#define SEQ     2048
#define BATCH   2
#define NTOK    (BATCH*SEQ)      // 4096
#define NHEAD   16
#define HDIM    128
#define FF      8192

typedef float  f32x4  __attribute__((ext_vector_type(4)));
typedef __bf16 bf16x8 __attribute__((ext_vector_type(8)));

__device__ __forceinline__ unsigned short f2bfbits(float f) {
    unsigned u = __builtin_bit_cast(unsigned, f);
    return (unsigned short)((u + 0x7fffu + ((u >> 16) & 1u)) >> 16);
}
__device__ __forceinline__ __bf16 f2bf(float f) {
    unsigned short h = f2bfbits(f);
    return __builtin_bit_cast(__bf16, h);
}

__device__ __forceinline__ void gld_lds16(const void* g, void* l) {
    __builtin_amdgcn_global_load_lds(
        (const __attribute__((address_space(1))) unsigned int*)g,
        (__attribute__((address_space(3))) unsigned int*)l, 16, 0, 0);
}

// ---------------- f32 -> bf16 convert (4 elems/thread) ----------------
__global__ __launch_bounds__(256) void cvt_f32_bf16(
        const float* __restrict__ in, __bf16* __restrict__ out) {
    int i = blockIdx.x * 256 + threadIdx.x;
    float4 v = ((const float4*)in)[i];
    ushort4 o;
    o.x = f2bfbits(v.x); o.y = f2bfbits(v.y);
    o.z = f2bfbits(v.z); o.w = f2bfbits(v.w);
    ((ushort4*)out)[i] = o;
}

// ---------------- LayerNorm: f32 in -> bf16 out, one block per row ----------------
__global__ __launch_bounds__(256) void ln_bf16(
        const float* __restrict__ x, const float* __restrict__ w,
        const float* __restrict__ b, __bf16* __restrict__ out) {
    const int row = blockIdx.x;
    const int tid = threadIdx.x;
    const float* xr = x + (size_t)row * D_MODEL;
    float4 v0 = *(const float4*)(xr + tid * 8);
    float4 v1 = *(const float4*)(xr + tid * 8 + 4);
    float va[8] = {v0.x, v0.y, v0.z, v0.w, v1.x, v1.y, v1.z, v1.w};
    float s = 0.f, ss = 0.f;
#pragma unroll
    for (int j = 0; j < 8; ++j) { s += va[j]; ss += va[j] * va[j]; }
#pragma unroll
    for (int m = 32; m; m >>= 1) { s += __shfl_xor(s, m, 64); ss += __shfl_xor(ss, m, 64); }
    __shared__ float red[8];
    const int wid = tid >> 6;
    if ((tid & 63) == 0) { red[wid * 2] = s; red[wid * 2 + 1] = ss; }
    __syncthreads();
    s  = red[0] + red[2] + red[4] + red[6];
    ss = red[1] + red[3] + red[5] + red[7];
    const float mu   = s * (1.0f / D_MODEL);
    const float var  = ss * (1.0f / D_MODEL) - mu * mu;
    const float rstd = rsqrtf(var + 1e-5f);
    const int c = tid * 8;
    ushort4 o0, o1;
    unsigned short ob[8];
#pragma unroll
    for (int j = 0; j < 8; ++j)
        ob[j] = f2bfbits((va[j] - mu) * rstd * w[c + j] + b[c + j]);
    o0.x = ob[0]; o0.y = ob[1]; o0.z = ob[2]; o0.w = ob[3];
    o1.x = ob[4]; o1.y = ob[5]; o1.z = ob[6]; o1.w = ob[7];
    ushort4* op = (ushort4*)(out + (size_t)row * D_MODEL + c);
    op[0] = o0; op[1] = o1;
}

// ---------------- GEMM (256x256 8-phase): C[M,N] = A[M,K] @ B[N,K]^T --------------
// 512 threads = 8 waves (2M x 4N), per-wave 128x64 output (acc[8][4] of 16x16).
// BK=64, LDS = 2 buffers x (A 256x64 + B 256x64) bf16 = 128 KiB.
// st_16x32 swizzle: lds_byte = lin ^ (((lin>>9)&1)<<5); applied on the global
// SOURCE for global_load_lds staging (rule #21) and on ds_read addresses.
// Per K-tile: 4 phases, each {ds-read subtile | stage 1 half-tile -> barrier ->
// lgkmcnt(0) -> setprio(1) -> 16 MFMA -> setprio(0) -> barrier}. Counted
// vmcnt(4) once per tile (phase 4). Staging slots chosen so each gld lands
// only in a region whose previous occupant died at an earlier barrier:
//   P1: (t+1).A half0   [buf^1 A: dead since (t-1).P3 barrier]
//   P2: (t+1).A half1
//   P3: (t+2).B half0   [buf B: tile t's B dead at t.P2 barrier]
//   P4: (t+2).B half1
// EPI: 0 = bf16 out, 1 = exact-GELU bf16 out, 2 = f32 out + residual,
//      3 = bf16 out transposed to [b, h, hd, s]
template <int EPI>
__global__ __launch_bounds__(512, 2) void gemm_bt8(
        const __bf16* __restrict__ A, const __bf16* __restrict__ Bm,
        __bf16* __restrict__ Cb, float* __restrict__ Cf,
        const float* __restrict__ resid, int M, int N, int K) {
    __shared__ __align__(16) __bf16 lds[2][2][256 * 64];
    const int tid = threadIdx.x;
    const int wid = tid >> 6, lane = tid & 63;
    const int l16 = lane & 15, lhi = lane >> 4;
    const int wm = wid >> 2, wn = wid & 3;

    // XCD-aware swizzle (launcher guarantees gridDim.x % 8 == 0)
    const int nbn = N >> 8;
    int id = blockIdx.x;
    const int cpx = gridDim.x >> 3;
    id = (id & 7) * cpx + (id >> 3);
    const int bm = id / nbn, bn = id % nbn;

    const __bf16* Ag = A  + (size_t)bm * 256 * K;
    const __bf16* Bg = Bm + (size_t)bn * 256 * K;
    const int NT = K >> 6;

    // stage one half-tile (16 KB): 2 x gld_lds16 per thread, linear LDS dest,
    // inverse-swizzled global source column
    auto stage = [&](__bf16* region, const __bf16* G, int kt, int half) {
#pragma unroll
        for (int j = 0; j < 2; ++j) {
            int idx = j * 512 + tid;            // 0..1023
            int r128 = idx >> 3;                // 0..127
            int Xc = (idx & 7) << 4;            // dest byte col 0..112
            int Xs = Xc ^ ((r128 & 4) << 3);    // source col: undo swizzle
            gld_lds16((const char*)(G + ((size_t)(half * 128 + r128) * K + kt * 64)) + Xs,
                      (char*)region + half * 16384 + idx * 16);
        }
    };

    f32x4 acc[8][4] = {};
    bf16x8 af0[4][2], af1[4][2], bq0[2][2], bq1[2][2];

    const __bf16* Abase;
    const __bf16* Bbase;
    auto ldA = [&](bf16x8 (&dst)[4][2], int qm) {
#pragma unroll
        for (int i = 0; i < 4; ++i)
#pragma unroll
            for (int ks = 0; ks < 2; ++ks) {
                int r = wm * 128 + (qm * 4 + i) * 16 + l16;
                int X = ks * 64 + lhi * 16;
                dst[i][ks] = *(const bf16x8*)((const char*)Abase + r * 128 + (X ^ ((r & 4) << 3)));
            }
    };
    auto ldB = [&](bf16x8 (&dst)[2][2], int qn) {
#pragma unroll
        for (int j = 0; j < 2; ++j)
#pragma unroll
            for (int ks = 0; ks < 2; ++ks) {
                int r = wn * 64 + (qn * 2 + j) * 16 + l16;
                int X = ks * 64 + lhi * 16;
                dst[j][ks] = *(const bf16x8*)((const char*)Bbase + r * 128 + (X ^ ((r & 4) << 3)));
            }
    };
    auto mfmaQ = [&](bf16x8 (&a)[4][2], bf16x8 (&b)[2][2], int mo, int no) {
        __builtin_amdgcn_s_setprio(1);
#pragma unroll
        for (int i = 0; i < 4; ++i)
#pragma unroll
            for (int j = 0; j < 2; ++j)
#pragma unroll
                for (int ks = 0; ks < 2; ++ks)
                    acc[mo + i][no + j] = __builtin_amdgcn_mfma_f32_16x16x32_bf16(
                        a[i][ks], b[j][ks], acc[mo + i][no + j], 0, 0, 0);
        __builtin_amdgcn_s_setprio(0);
    };

    // prologue: tile0 A+B, tile1 B; wait until tile0 landed (4 gld may remain)
    stage(&lds[0][0][0], Ag, 0, 0); stage(&lds[0][0][0], Ag, 0, 1);
    stage(&lds[0][1][0], Bg, 0, 0); stage(&lds[0][1][0], Bg, 0, 1);
    if (NT > 1) {
        stage(&lds[1][1][0], Bg, 1, 0); stage(&lds[1][1][0], Bg, 1, 1);
        asm volatile("s_waitcnt vmcnt(4)" ::: "memory");
    } else {
        asm volatile("s_waitcnt vmcnt(0)" ::: "memory");
    }
    __builtin_amdgcn_s_barrier();

    for (int t = 0; t < NT; ++t) {
        const int cur = t & 1;
        Abase = &lds[cur][0][0];
        Bbase = &lds[cur][1][0];
        // P1: read A(qm=0) + B(qn=0); stage (t+1).A half0
        ldA(af0, 0);
        ldB(bq0, 0);
        if (t + 1 < NT) stage(&lds[cur ^ 1][0][0], Ag, t + 1, 0);
        __builtin_amdgcn_s_barrier();
        asm volatile("s_waitcnt lgkmcnt(0)" ::: "memory");
        mfmaQ(af0, bq0, 0, 0);
        __builtin_amdgcn_s_barrier();
        // P2: read B(qn=1); stage (t+1).A half1
        ldB(bq1, 1);
        if (t + 1 < NT) stage(&lds[cur ^ 1][0][0], Ag, t + 1, 1);
        __builtin_amdgcn_s_barrier();
        asm volatile("s_waitcnt lgkmcnt(0)" ::: "memory");
        mfmaQ(af0, bq1, 0, 2);
        __builtin_amdgcn_s_barrier();
        // P3: read A(qm=1); stage (t+2).B half0
        ldA(af1, 1);
        if (t + 2 < NT) stage(&lds[cur][1][0], Bg, t + 2, 0);
        __builtin_amdgcn_s_barrier();
        asm volatile("s_waitcnt lgkmcnt(0)" ::: "memory");
        mfmaQ(af1, bq0, 4, 0);
        __builtin_amdgcn_s_barrier();
        // P4: stage (t+2).B half1; counted vmcnt at tile end (never 0 mid-loop)
        if (t + 2 < NT) stage(&lds[cur][1][0], Bg, t + 2, 1);
        __builtin_amdgcn_s_barrier();
        asm volatile("s_waitcnt lgkmcnt(0)" ::: "memory");
        mfmaQ(af1, bq1, 4, 2);
        if (t + 2 < NT)      asm volatile("s_waitcnt vmcnt(4)" ::: "memory");
        else if (t + 1 < NT) asm volatile("s_waitcnt vmcnt(0)" ::: "memory");
        __builtin_amdgcn_s_barrier();
    }

#pragma unroll
    for (int m = 0; m < 8; ++m) {
        const int row = bm * 256 + wm * 128 + m * 16 + lhi * 4;
#pragma unroll
        for (int n = 0; n < 4; ++n) {
            const int col = bn * 256 + wn * 64 + n * 16 + l16;
            if (EPI == 3) {
                const int h = col >> 7, hd = col & 127;
                const size_t obase =
                    ((((size_t)(row >> 11) * NHEAD + h) * HDIM + hd) << 11) + (row & 2047);
                ushort4 o;
                o.x = f2bfbits(acc[m][n][0]); o.y = f2bfbits(acc[m][n][1]);
                o.z = f2bfbits(acc[m][n][2]); o.w = f2bfbits(acc[m][n][3]);
                *(ushort4*)((unsigned short*)Cb + obase) = o;
            } else {
#pragma unroll
                for (int r = 0; r < 4; ++r) {
                    float v = acc[m][n][r];
                    size_t off = (size_t)(row + r) * N + col;
                    if (EPI == 0) {
                        Cb[off] = f2bf(v);
                    } else if (EPI == 1) {
                        Cb[off] = f2bf(0.5f * v * (1.0f + erff(v * 0.70710678118654752f)));
                    } else {
                        Cf[off] = v + resid[off];
                    }
                }
            }
        }
    }
}

// ---------------- Causal flash attention ----------------
// grid: (S/64, NHEAD, BATCH), 256 threads. Wave w owns Q rows [qt*64+w*16, +16).
// qt remapped heavy-first for causal load balance. K staged via global_load_lds
// with XOR-swizzled SOURCE (rule #21). V comes in pre-transposed [b,h,d,s] from
// the V-projection GEMM and is staged the same way. Online softmax in base-2.
__global__ __launch_bounds__(256) void attn_causal(
        const __bf16* __restrict__ Q, const __bf16* __restrict__ K,
        const __bf16* __restrict__ Vt, __bf16* __restrict__ O) {
    const int qt = gridDim.x - 1 - blockIdx.x;   // heavy blocks first
    const int h = blockIdx.y, bb = blockIdx.z;
    const int tid = threadIdx.x, wid = tid >> 6, lane = tid & 63;
    const int l16 = lane & 15, lhi = lane >> 4;
    __shared__ __align__(16) __bf16 Ks[64 * 128];   // [tok][d], chunk-swizzled
    __shared__ __align__(16) __bf16 Vs[128 * 64];   // [d][tok], chunk-swizzled
    __shared__ __align__(16) __bf16 Pl[4][16 * 72]; // per-wave P [q][tok], pad 72

    const size_t base   = ((size_t)bb * SEQ) * D_MODEL + (size_t)h * HDIM;
    const size_t vtbase = (((size_t)bb * NHEAD + h) * HDIM) << 11;  // [d][s], row=2048
    const int q0 = qt * 64 + wid * 16;

    bf16x8 qf[4];
#pragma unroll
    for (int ks = 0; ks < 4; ++ks)
        qf[ks] = *(const bf16x8*)(Q + base + (size_t)(q0 + l16) * D_MODEL + ks * 32 + lhi * 8);

    f32x4 accO[8] = {};
    float m_run[4], l_run[4];
#pragma unroll
    for (int r = 0; r < 4; ++r) { m_run[r] = -1e30f; l_run[r] = 0.f; }

    // 1/sqrt(128) * log2(e): softmax carried in base-2 domain
    const float scale2 = 0.08838834764831845f * 1.4426950408889634f;

    for (int kt = 0; kt <= qt; ++kt) {
        // stage K [64 tok][16 chunks], source pre-swizzled
#pragma unroll
        for (int i = 0; i < 4; ++i) {
            int idx = i * 256 + tid;
            int row = idx >> 4, c8 = idx & 15;
            int c8s = c8 ^ (row & 7);
            gld_lds16(K + base + (size_t)(kt * 64 + row) * D_MODEL + c8s * 8, Ks + idx * 8);
        }
        // stage V^T [128 d][8 chunks of 8 tok], same swizzle scheme
#pragma unroll
        for (int i = 0; i < 4; ++i) {
            int idx = i * 256 + tid;
            int row = idx >> 3, c8 = idx & 7;
            int c8s = c8 ^ (row & 7);
            gld_lds16(Vt + vtbase + (size_t)row * SEQ + kt * 64 + c8s * 8, Vs + idx * 8);
        }
        __syncthreads();

        // QK^T : s[nb] covers toks nb*16+l16, rows lhi*4+r
        f32x4 s[4] = {};
        __builtin_amdgcn_s_setprio(1);
#pragma unroll
        for (int nb = 0; nb < 4; ++nb) {
            const int tok = nb * 16 + l16;
#pragma unroll
            for (int ks = 0; ks < 4; ++ks) {
                int co = (ks * 64 + lhi * 16) ^ ((tok & 7) << 4);
                bf16x8 kf = *(const bf16x8*)((const char*)Ks + tok * 256 + co);
                s[nb] = __builtin_amdgcn_mfma_f32_16x16x32_bf16(qf[ks], kf, s[nb], 0, 0, 0);
            }
        }
        __builtin_amdgcn_s_setprio(0);
        const bool diag = (kt == qt);
#pragma unroll
        for (int nb = 0; nb < 4; ++nb)
#pragma unroll
            for (int r = 0; r < 4; ++r) {
                float sv = s[nb][r] * scale2;
                if (diag && (nb * 16 + l16) > (wid * 16 + lhi * 4 + r)) sv = -1e30f;
                s[nb][r] = sv;
            }
        float alpha[4];
#pragma unroll
        for (int r = 0; r < 4; ++r) {
            float mx = fmaxf(fmaxf(s[0][r], s[1][r]), fmaxf(s[2][r], s[3][r]));
#pragma unroll
            for (int m = 8; m; m >>= 1) mx = fmaxf(mx, __shfl_xor(mx, m, 64));
            float mnew = fmaxf(m_run[r], mx);
            alpha[r] = exp2f(m_run[r] - mnew);
            float rs = 0.f;
#pragma unroll
            for (int nb = 0; nb < 4; ++nb) {
                float p = exp2f(s[nb][r] - mnew);
                s[nb][r] = p;
                rs += p;
            }
#pragma unroll
            for (int m = 8; m; m >>= 1) rs += __shfl_xor(rs, m, 64);
            l_run[r] = l_run[r] * alpha[r] + rs;
            m_run[r] = mnew;
        }
#pragma unroll
        for (int d8 = 0; d8 < 8; ++d8)
#pragma unroll
            for (int r = 0; r < 4; ++r) accO[d8][r] *= alpha[r];
        // P -> LDS in A-fragment layout [q][tok]
#pragma unroll
        for (int nb = 0; nb < 4; ++nb)
#pragma unroll
            for (int r = 0; r < 4; ++r)
                Pl[wid][(lhi * 4 + r) * 72 + nb * 16 + l16] = f2bf(s[nb][r]);
        // PV: vf = V^T[d = d8*16+l16][tok chunk (ks2*4+lhi) ^ (d&7)]
        __builtin_amdgcn_s_setprio(1);
#pragma unroll
        for (int ks2 = 0; ks2 < 2; ++ks2) {
            bf16x8 pa = *(const bf16x8*)(&Pl[wid][l16 * 72 + ks2 * 32 + lhi * 8]);
#pragma unroll
            for (int d8 = 0; d8 < 8; ++d8) {
                const int d = d8 * 16 + l16;
                const int co = ((ks2 * 4 + lhi) ^ (d & 7)) << 4;
                bf16x8 vf = *(const bf16x8*)((const char*)Vs + d * 128 + co);
                accO[d8] = __builtin_amdgcn_mfma_f32_16x16x32_bf16(pa, vf, accO[d8], 0, 0, 0);
            }
        }
        __builtin_amdgcn_s_setprio(0);
        __syncthreads();
    }

#pragma unroll
    for (int d8 = 0; d8 < 8; ++d8)
#pragma unroll
        for (int r = 0; r < 4; ++r) {
            float o = accO[d8][r] / l_run[r];
            O[base + (size_t)(q0 + lhi * 4 + r) * D_MODEL + d8 * 16 + l16] = f2bf(o);
        }
}

// ---------------- host launcher ----------------
extern "C" void kernel_launch(void* const* d_in, const int* in_sizes, int n_in,
                              void* d_out, int out_size, void* d_ws, size_t ws_size,
                              hipStream_t stream) {
    const float* x    = (const float*)d_in[0];
    const float* tok  = (const float*)d_in[1];
    const float* Wq   = (const float*)d_in[2];
    const float* Wk   = (const float*)d_in[3];
    const float* Wv   = (const float*)d_in[4];
    const float* Wo   = (const float*)d_in[5];
    const float* W1   = (const float*)d_in[6];
    const float* W2   = (const float*)d_in[7];
    const float* ln1w = (const float*)d_in[8];
    const float* ln1b = (const float*)d_in[9];
    const float* ln2w = (const float*)d_in[10];
    const float* ln2b = (const float*)d_in[11];
    float* out = (float*)d_out;

    char* ws = (char*)d_ws;
    size_t off = 0;
    auto alloc = [&](size_t bytes) { void* p = ws + off; off += bytes; return p; };
    __bf16* tokb  = (__bf16*)alloc((size_t)NTOK * D_MODEL * 2);       // 16 MB
    __bf16* hnorm = (__bf16*)alloc((size_t)NTOK * D_MODEL * 2);       // 16 MB (reused as h2)
    __bf16* wqb   = (__bf16*)alloc((size_t)D_MODEL * D_MODEL * 2);
    __bf16* wkb   = (__bf16*)alloc((size_t)D_MODEL * D_MODEL * 2);
    __bf16* wvb   = (__bf16*)alloc((size_t)D_MODEL * D_MODEL * 2);
    __bf16* wob   = (__bf16*)alloc((size_t)D_MODEL * D_MODEL * 2);
    __bf16* w1b   = (__bf16*)alloc((size_t)FF * D_MODEL * 2);
    __bf16* w2b   = (__bf16*)alloc((size_t)D_MODEL * FF * 2);
    __bf16* Qb    = (__bf16*)alloc((size_t)NTOK * D_MODEL * 2);
    __bf16* Kb    = (__bf16*)alloc((size_t)NTOK * D_MODEL * 2);
    __bf16* Vtg   = (__bf16*)alloc((size_t)NTOK * D_MODEL * 2);       // V^T [b,h,d,s]
    __bf16* Ab    = (__bf16*)alloc((size_t)NTOK * D_MODEL * 2);
    __bf16* gb    = Qb;  // FFN intermediate aliases Qb..Ab (64 MB, all dead by then)
    float*  x2    = (float*)alloc((size_t)NTOK * D_MODEL * 4);        // 32 MB

    // converts
    cvt_f32_bf16<<<(NTOK * D_MODEL) / 1024, 256, 0, stream>>>(tok, tokb);
    cvt_f32_bf16<<<(D_MODEL * D_MODEL) / 1024, 256, 0, stream>>>(Wq, wqb);
    cvt_f32_bf16<<<(D_MODEL * D_MODEL) / 1024, 256, 0, stream>>>(Wk, wkb);
    cvt_f32_bf16<<<(D_MODEL * D_MODEL) / 1024, 256, 0, stream>>>(Wv, wvb);
    cvt_f32_bf16<<<(D_MODEL * D_MODEL) / 1024, 256, 0, stream>>>(Wo, wob);
    cvt_f32_bf16<<<(FF * D_MODEL) / 1024, 256, 0, stream>>>(W1, w1b);
    cvt_f32_bf16<<<(FF * D_MODEL) / 1024, 256, 0, stream>>>(W2, w2b);

    ln_bf16<<<NTOK, 256, 0, stream>>>(x, ln1w, ln1b, hnorm);

    const int g_sq = (NTOK / 256) * (D_MODEL / 256);   // 16*8 = 128 blocks
    const int g_ff = (NTOK / 256) * (FF / 256);        // 16*32 = 512 blocks
    gemm_bt8<0><<<g_sq, 512, 0, stream>>>(hnorm, wqb, Qb, nullptr, nullptr, NTOK, D_MODEL, D_MODEL);
    gemm_bt8<0><<<g_sq, 512, 0, stream>>>(hnorm, wkb, Kb, nullptr, nullptr, NTOK, D_MODEL, D_MODEL);
    gemm_bt8<3><<<g_sq, 512, 0, stream>>>(tokb, wvb, Vtg, nullptr, nullptr, NTOK, D_MODEL, D_MODEL);

    attn_causal<<<dim3(SEQ / 64, NHEAD, BATCH), 256, 0, stream>>>(Qb, Kb, Vtg, Ab);

    gemm_bt8<2><<<g_sq, 512, 0, stream>>>(Ab, wob, nullptr, x2, x, NTOK, D_MODEL, D_MODEL);

    ln_bf16<<<NTOK, 256, 0, stream>>>(x2, ln2w, ln2b, hnorm);   // h2

    gemm_bt8<1><<<g_ff, 512, 0, stream>>>(hnorm, w1b, gb, nullptr, nullptr, NTOK, FF, D_MODEL);
    gemm_bt8<2><<<g_sq, 512, 0, stream>>>(gb, w2b, nullptr, out, x2, NTOK, D_MODEL, FF);
}

// Round 5
// 900.801 us; speedup vs baseline: 1.3100x; 1.0659x over previous
//
#include <hip/hip_runtime.h>
#include <hip/hip_bf16.h>
#include <math.h>

#define D_MODEL 2048
#define SEQ     2048
#define BATCH   2
#define NTOK    (BATCH*SEQ)      // 4096
#define NHEAD   16
#define HDIM    128
#define FF      8192

typedef float  f32x4  __attribute__((ext_vector_type(4)));
typedef __bf16 bf16x8 __attribute__((ext_vector_type(8)));

__device__ __forceinline__ unsigned short f2bfbits(float f) {
    unsigned u = __builtin_bit_cast(unsigned, f);
    return (unsigned short)((u + 0x7fffu + ((u >> 16) & 1u)) >> 16);
}
__device__ __forceinline__ __bf16 f2bf(float f) {
    unsigned short h = f2bfbits(f);
    return __builtin_bit_cast(__bf16, h);
}

__device__ __forceinline__ void gld_lds16(const void* g, void* l) {
    __builtin_amdgcn_global_load_lds(
        (const __attribute__((address_space(1))) unsigned int*)g,
        (__attribute__((address_space(3))) unsigned int*)l, 16, 0, 0);
}

// ---------------- f32 -> bf16 convert (4 elems/thread) ----------------
__global__ __launch_bounds__(256) void cvt_f32_bf16(
        const float* __restrict__ in, __bf16* __restrict__ out) {
    int i = blockIdx.x * 256 + threadIdx.x;
    float4 v = ((const float4*)in)[i];
    ushort4 o;
    o.x = f2bfbits(v.x); o.y = f2bfbits(v.y);
    o.z = f2bfbits(v.z); o.w = f2bfbits(v.w);
    ((ushort4*)out)[i] = o;
}

// ---------------- split-K reduce: out = p0 + p1 + resid (f32) ----------------
__global__ __launch_bounds__(256) void add_reduce(
        const float* __restrict__ p0, const float* __restrict__ p1,
        const float* __restrict__ resid, float* __restrict__ out) {
    int i = blockIdx.x * 256 + threadIdx.x;
    float4 a = ((const float4*)p0)[i];
    float4 b = ((const float4*)p1)[i];
    float4 r = ((const float4*)resid)[i];
    float4 o;
    o.x = a.x + b.x + r.x; o.y = a.y + b.y + r.y;
    o.z = a.z + b.z + r.z; o.w = a.w + b.w + r.w;
    ((float4*)out)[i] = o;
}

// ---------------- LayerNorm: f32 in -> bf16 out, one block per row ----------------
__global__ __launch_bounds__(256) void ln_bf16(
        const float* __restrict__ x, const float* __restrict__ w,
        const float* __restrict__ b, __bf16* __restrict__ out) {
    const int row = blockIdx.x;
    const int tid = threadIdx.x;
    const float* xr = x + (size_t)row * D_MODEL;
    float4 v0 = *(const float4*)(xr + tid * 8);
    float4 v1 = *(const float4*)(xr + tid * 8 + 4);
    float va[8] = {v0.x, v0.y, v0.z, v0.w, v1.x, v1.y, v1.z, v1.w};
    float s = 0.f, ss = 0.f;
#pragma unroll
    for (int j = 0; j < 8; ++j) { s += va[j]; ss += va[j] * va[j]; }
#pragma unroll
    for (int m = 32; m; m >>= 1) { s += __shfl_xor(s, m, 64); ss += __shfl_xor(ss, m, 64); }
    __shared__ float red[8];
    const int wid = tid >> 6;
    if ((tid & 63) == 0) { red[wid * 2] = s; red[wid * 2 + 1] = ss; }
    __syncthreads();
    s  = red[0] + red[2] + red[4] + red[6];
    ss = red[1] + red[3] + red[5] + red[7];
    const float mu   = s * (1.0f / D_MODEL);
    const float var  = ss * (1.0f / D_MODEL) - mu * mu;
    const float rstd = rsqrtf(var + 1e-5f);
    const int c = tid * 8;
    ushort4 o0, o1;
    unsigned short ob[8];
#pragma unroll
    for (int j = 0; j < 8; ++j)
        ob[j] = f2bfbits((va[j] - mu) * rstd * w[c + j] + b[c + j]);
    o0.x = ob[0]; o0.y = ob[1]; o0.z = ob[2]; o0.w = ob[3];
    o1.x = ob[4]; o1.y = ob[5]; o1.z = ob[6]; o1.w = ob[7];
    ushort4* op = (ushort4*)(out + (size_t)row * D_MODEL + c);
    op[0] = o0; op[1] = o1;
}

// ---------------- GEMM (256x256, 4-phase, deep prefetch): C = A @ B^T ------------
// 512 threads = 8 waves (2M x 4N), per-wave 128x64 (acc[8][4] of 16x16x32).
// BK=64, LDS = 2 tile-buffers x (A 32KB + B 32KB) = 128 KiB.
// Swizzle (both-sides, rule #21): chunk col X ^= ((r&4)<<3) ^ ((r&8)<<1)
//   -> 16 consecutive rows spread over 4 distinct 16B slots (4-way max).
// Staging: ALL 4 half-tiles of tile t+1 issued at t.P1 (buf^1 is dead: its
// last reads drained at t-1.P3 lgkmcnt(0), all waves past t-1 final barrier).
// vmcnt(0) only at t.P4-end => wait distance ~3.5 phases > HBM latency.
// EPI: 0 bf16 | 1 GELU bf16 | 2 f32+resid | 3 bf16 transposed [b,h,hd,s] | 4 f32 partial
template <int EPI, int SPLITK>
__global__ __launch_bounds__(512, 2) void gemm_bt8(
        const __bf16* __restrict__ A, const __bf16* __restrict__ Bm,
        __bf16* __restrict__ Cb, float* __restrict__ Cf,
        const float* __restrict__ resid, int M, int N, int K) {
    __shared__ __align__(16) __bf16 lds[2][2][256 * 64];
    const int tid = threadIdx.x;
    const int wid = tid >> 6, lane = tid & 63;
    const int l16 = lane & 15, lhi = lane >> 4;
    const int wm = wid >> 2, wn = wid & 3;

    // XCD-aware swizzle (launcher guarantees gridDim.x % 8 == 0)
    int id = blockIdx.x;
    const int cpx = gridDim.x >> 3;
    id = (id & 7) * cpx + (id >> 3);
    const int nbn = N >> 8;
    int slice = 0;
    if (SPLITK == 2) {
        const int nblk = (M >> 8) * nbn;
        slice = id / nblk;
        id -= slice * nblk;
    }
    const int bm = id / nbn, bn = id % nbn;

    const __bf16* Ag = A  + (size_t)bm * 256 * K;
    const __bf16* Bg = Bm + (size_t)bn * 256 * K;
    const int tps = (K >> 6) / SPLITK;       // tiles per slice
    const int t0 = slice * tps, t1 = t0 + tps;

    auto stage = [&](__bf16* region, const __bf16* G, int kt, int half) {
#pragma unroll
        for (int j = 0; j < 2; ++j) {
            int idx = j * 512 + tid;            // 0..1023
            int r128 = idx >> 3;                // row within half
            int Xc = (idx & 7) << 4;            // dest byte col
            int Xs = Xc ^ ((r128 & 4) << 3) ^ ((r128 & 8) << 1);
            gld_lds16((const char*)(G + ((size_t)(half * 128 + r128) * K + kt * 64)) + Xs,
                      (char*)region + half * 16384 + idx * 16);
        }
    };

    f32x4 acc[8][4] = {};
    bf16x8 af0[4][2], af1[4][2], bq0[2][2], bq1[2][2];

    const __bf16* Abase;
    const __bf16* Bbase;
    auto ldA = [&](bf16x8 (&dst)[4][2], int qm) {
#pragma unroll
        for (int i = 0; i < 4; ++i)
#pragma unroll
            for (int ks = 0; ks < 2; ++ks) {
                int r = wm * 128 + (qm * 4 + i) * 16 + l16;
                int X = ks * 64 + lhi * 16;
                dst[i][ks] = *(const bf16x8*)((const char*)Abase + r * 128 +
                                              (X ^ ((r & 4) << 3) ^ ((r & 8) << 1)));
            }
    };
    auto ldB = [&](bf16x8 (&dst)[2][2], int qn) {
#pragma unroll
        for (int j = 0; j < 2; ++j)
#pragma unroll
            for (int ks = 0; ks < 2; ++ks) {
                int r = wn * 64 + (qn * 2 + j) * 16 + l16;
                int X = ks * 64 + lhi * 16;
                dst[j][ks] = *(const bf16x8*)((const char*)Bbase + r * 128 +
                                              (X ^ ((r & 4) << 3) ^ ((r & 8) << 1)));
            }
    };
    auto mfmaQ = [&](bf16x8 (&a)[4][2], bf16x8 (&b)[2][2], int mo, int no) {
        __builtin_amdgcn_s_setprio(1);
#pragma unroll
        for (int i = 0; i < 4; ++i)
#pragma unroll
            for (int j = 0; j < 2; ++j)
#pragma unroll
                for (int ks = 0; ks < 2; ++ks)
                    acc[mo + i][no + j] = __builtin_amdgcn_mfma_f32_16x16x32_bf16(
                        a[i][ks], b[j][ks], acc[mo + i][no + j], 0, 0, 0);
        __builtin_amdgcn_s_setprio(0);
    };

    // prologue: tile t0 fully staged, drained
    stage(&lds[0][0][0], Ag, t0, 0); stage(&lds[0][0][0], Ag, t0, 1);
    stage(&lds[0][1][0], Bg, t0, 0); stage(&lds[0][1][0], Bg, t0, 1);
    asm volatile("s_waitcnt vmcnt(0)" ::: "memory");
    __builtin_amdgcn_s_barrier();

    for (int t = t0; t < t1; ++t) {
        const int cur = (t - t0) & 1;
        Abase = &lds[cur][0][0];
        Bbase = &lds[cur][1][0];
        const bool pf = (t + 1 < t1);
        // P1: issue ALL of tile t+1's staging (max wait distance); read q(0,0) frags
        if (pf) {
            stage(&lds[cur ^ 1][0][0], Ag, t + 1, 0);
            stage(&lds[cur ^ 1][0][0], Ag, t + 1, 1);
            stage(&lds[cur ^ 1][1][0], Bg, t + 1, 0);
            stage(&lds[cur ^ 1][1][0], Bg, t + 1, 1);
        }
        ldA(af0, 0); ldB(bq0, 0);
        __builtin_amdgcn_s_barrier();
        asm volatile("s_waitcnt lgkmcnt(0)" ::: "memory");
        __builtin_amdgcn_sched_barrier(0);   // rule #18: pin MFMA below the waitcnt
        mfmaQ(af0, bq0, 0, 0);
        __builtin_amdgcn_s_barrier();
        // P2
        ldB(bq1, 1);
        __builtin_amdgcn_s_barrier();
        asm volatile("s_waitcnt lgkmcnt(0)" ::: "memory");
        __builtin_amdgcn_sched_barrier(0);
        mfmaQ(af0, bq1, 0, 2);
        __builtin_amdgcn_s_barrier();
        // P3
        ldA(af1, 1);
        __builtin_amdgcn_s_barrier();
        asm volatile("s_waitcnt lgkmcnt(0)" ::: "memory");
        __builtin_amdgcn_sched_barrier(0);
        mfmaQ(af1, bq0, 4, 0);
        __builtin_amdgcn_s_barrier();
        // P4: register-only MFMA, then drain next tile's loads (issued 3.5 phases ago)
        mfmaQ(af1, bq1, 4, 2);
        if (pf) asm volatile("s_waitcnt vmcnt(0)" ::: "memory");
        __builtin_amdgcn_s_barrier();
    }

#pragma unroll
    for (int m = 0; m < 8; ++m) {
        const int row = bm * 256 + wm * 128 + m * 16 + lhi * 4;
#pragma unroll
        for (int n = 0; n < 4; ++n) {
            const int col = bn * 256 + wn * 64 + n * 16 + l16;
            if (EPI == 3) {
                const int h = col >> 7, hd = col & 127;
                const size_t obase =
                    ((((size_t)(row >> 11) * NHEAD + h) * HDIM + hd) << 11) + (row & 2047);
                ushort4 o;
                o.x = f2bfbits(acc[m][n][0]); o.y = f2bfbits(acc[m][n][1]);
                o.z = f2bfbits(acc[m][n][2]); o.w = f2bfbits(acc[m][n][3]);
                *(ushort4*)((unsigned short*)Cb + obase) = o;
            } else {
#pragma unroll
                for (int r = 0; r < 4; ++r) {
                    float v = acc[m][n][r];
                    size_t off = (size_t)(row + r) * N + col;
                    if (EPI == 0) {
                        Cb[off] = f2bf(v);
                    } else if (EPI == 1) {
                        Cb[off] = f2bf(0.5f * v * (1.0f + erff(v * 0.70710678118654752f)));
                    } else if (EPI == 2) {
                        Cf[off] = v + resid[off];
                    } else {  // EPI == 4: f32 partial per slice
                        Cf[(size_t)slice * M * N + off] = v;
                    }
                }
            }
        }
    }
}

// ---------------- Causal flash attention ----------------
// Q,K come from the fused QK buffer [4096 tok][4096] (Q cols 0..2047, K cols
// 2048..4095 passed as base+2048): row stride LDQK=4096. V pre-transposed
// [b,h,d,s]. K/V staged via global_load_lds with XOR-swizzled SOURCE.
#define LDQK 4096
__global__ __launch_bounds__(256) void attn_causal(
        const __bf16* __restrict__ Q, const __bf16* __restrict__ K,
        const __bf16* __restrict__ Vt, __bf16* __restrict__ O) {
    const int qt = gridDim.x - 1 - blockIdx.x;   // heavy blocks first
    const int h = blockIdx.y, bb = blockIdx.z;
    const int tid = threadIdx.x, wid = tid >> 6, lane = tid & 63;
    const int l16 = lane & 15, lhi = lane >> 4;
    __shared__ __align__(16) __bf16 Ks[64 * 128];   // [tok][d], chunk-swizzled
    __shared__ __align__(16) __bf16 Vs[128 * 64];   // [d][tok], chunk-swizzled
    __shared__ __align__(16) __bf16 Pl[4][16 * 72]; // per-wave P [q][tok], pad 72

    const size_t qkbase = ((size_t)bb * SEQ) * LDQK + (size_t)h * HDIM;
    const size_t obase  = ((size_t)bb * SEQ) * D_MODEL + (size_t)h * HDIM;
    const size_t vtbase = (((size_t)bb * NHEAD + h) * HDIM) << 11;  // [d][s]
    const int q0 = qt * 64 + wid * 16;

    bf16x8 qf[4];
#pragma unroll
    for (int ks = 0; ks < 4; ++ks)
        qf[ks] = *(const bf16x8*)(Q + qkbase + (size_t)(q0 + l16) * LDQK + ks * 32 + lhi * 8);

    f32x4 accO[8] = {};
    float m_run[4], l_run[4];
#pragma unroll
    for (int r = 0; r < 4; ++r) { m_run[r] = -1e30f; l_run[r] = 0.f; }

    const float scale2 = 0.08838834764831845f * 1.4426950408889634f;

    for (int kt = 0; kt <= qt; ++kt) {
#pragma unroll
        for (int i = 0; i < 4; ++i) {
            int idx = i * 256 + tid;
            int row = idx >> 4, c8 = idx & 15;
            int c8s = c8 ^ (row & 7);
            gld_lds16(K + qkbase + (size_t)(kt * 64 + row) * LDQK + c8s * 8, Ks + idx * 8);
        }
#pragma unroll
        for (int i = 0; i < 4; ++i) {
            int idx = i * 256 + tid;
            int row = idx >> 3, c8 = idx & 7;
            int c8s = c8 ^ (row & 7);
            gld_lds16(Vt + vtbase + (size_t)row * SEQ + kt * 64 + c8s * 8, Vs + idx * 8);
        }
        __syncthreads();

        f32x4 s[4] = {};
        __builtin_amdgcn_s_setprio(1);
#pragma unroll
        for (int nb = 0; nb < 4; ++nb) {
            const int tok = nb * 16 + l16;
#pragma unroll
            for (int ks = 0; ks < 4; ++ks) {
                int co = (ks * 64 + lhi * 16) ^ ((tok & 7) << 4);
                bf16x8 kf = *(const bf16x8*)((const char*)Ks + tok * 256 + co);
                s[nb] = __builtin_amdgcn_mfma_f32_16x16x32_bf16(qf[ks], kf, s[nb], 0, 0, 0);
            }
        }
        __builtin_amdgcn_s_setprio(0);
        const bool diag = (kt == qt);
#pragma unroll
        for (int nb = 0; nb < 4; ++nb)
#pragma unroll
            for (int r = 0; r < 4; ++r) {
                float sv = s[nb][r] * scale2;
                if (diag && (nb * 16 + l16) > (wid * 16 + lhi * 4 + r)) sv = -1e30f;
                s[nb][r] = sv;
            }
        float alpha[4];
#pragma unroll
        for (int r = 0; r < 4; ++r) {
            float mx = fmaxf(fmaxf(s[0][r], s[1][r]), fmaxf(s[2][r], s[3][r]));
#pragma unroll
            for (int m = 8; m; m >>= 1) mx = fmaxf(mx, __shfl_xor(mx, m, 64));
            float mnew = fmaxf(m_run[r], mx);
            alpha[r] = exp2f(m_run[r] - mnew);
            float rs = 0.f;
#pragma unroll
            for (int nb = 0; nb < 4; ++nb) {
                float p = exp2f(s[nb][r] - mnew);
                s[nb][r] = p;
                rs += p;
            }
#pragma unroll
            for (int m = 8; m; m >>= 1) rs += __shfl_xor(rs, m, 64);
            l_run[r] = l_run[r] * alpha[r] + rs;
            m_run[r] = mnew;
        }
#pragma unroll
        for (int d8 = 0; d8 < 8; ++d8)
#pragma unroll
            for (int r = 0; r < 4; ++r) accO[d8][r] *= alpha[r];
#pragma unroll
        for (int nb = 0; nb < 4; ++nb)
#pragma unroll
            for (int r = 0; r < 4; ++r)
                Pl[wid][(lhi * 4 + r) * 72 + nb * 16 + l16] = f2bf(s[nb][r]);
        __builtin_amdgcn_s_setprio(1);
#pragma unroll
        for (int ks2 = 0; ks2 < 2; ++ks2) {
            bf16x8 pa = *(const bf16x8*)(&Pl[wid][l16 * 72 + ks2 * 32 + lhi * 8]);
#pragma unroll
            for (int d8 = 0; d8 < 8; ++d8) {
                const int d = d8 * 16 + l16;
                const int co = ((ks2 * 4 + lhi) ^ (d & 7)) << 4;
                bf16x8 vf = *(const bf16x8*)((const char*)Vs + d * 128 + co);
                accO[d8] = __builtin_amdgcn_mfma_f32_16x16x32_bf16(pa, vf, accO[d8], 0, 0, 0);
            }
        }
        __builtin_amdgcn_s_setprio(0);
        __syncthreads();
    }

#pragma unroll
    for (int d8 = 0; d8 < 8; ++d8)
#pragma unroll
        for (int r = 0; r < 4; ++r) {
            float o = accO[d8][r] / l_run[r];
            O[obase + (size_t)(q0 + lhi * 4 + r) * D_MODEL + d8 * 16 + l16] = f2bf(o);
        }
}

// ---------------- host launcher ----------------
extern "C" void kernel_launch(void* const* d_in, const int* in_sizes, int n_in,
                              void* d_out, int out_size, void* d_ws, size_t ws_size,
                              hipStream_t stream) {
    const float* x    = (const float*)d_in[0];
    const float* tok  = (const float*)d_in[1];
    const float* Wq   = (const float*)d_in[2];
    const float* Wk   = (const float*)d_in[3];
    const float* Wv   = (const float*)d_in[4];
    const float* Wo   = (const float*)d_in[5];
    const float* W1   = (const float*)d_in[6];
    const float* W2   = (const float*)d_in[7];
    const float* ln1w = (const float*)d_in[8];
    const float* ln1b = (const float*)d_in[9];
    const float* ln2w = (const float*)d_in[10];
    const float* ln2b = (const float*)d_in[11];
    float* out = (float*)d_out;

    char* ws = (char*)d_ws;
    size_t off = 0;
    auto alloc = [&](size_t bytes) { void* p = ws + off; off += bytes; return p; };
    __bf16* tokb  = (__bf16*)alloc((size_t)NTOK * D_MODEL * 2);       //   0-16 MB
    __bf16* hnorm = (__bf16*)alloc((size_t)NTOK * D_MODEL * 2);       //  16-32
    __bf16* wqb   = (__bf16*)alloc((size_t)D_MODEL * D_MODEL * 2);    //  32-40 (wq|wk adjacent = fused QK weight)
    __bf16* wkb   = (__bf16*)alloc((size_t)D_MODEL * D_MODEL * 2);    //  40-48
    __bf16* wvb   = (__bf16*)alloc((size_t)D_MODEL * D_MODEL * 2);    //  48-56
    __bf16* wob   = (__bf16*)alloc((size_t)D_MODEL * D_MODEL * 2);    //  56-64
    __bf16* w1b   = (__bf16*)alloc((size_t)FF * D_MODEL * 2);         //  64-96
    __bf16* w2b   = (__bf16*)alloc((size_t)D_MODEL * FF * 2);         //  96-128
    __bf16* QKb   = (__bf16*)alloc((size_t)NTOK * 2 * D_MODEL * 2);   // 128-160 (fused [tok][4096])
    __bf16* Vtg   = (__bf16*)alloc((size_t)NTOK * D_MODEL * 2);       // 160-176 V^T [b,h,d,s]
    __bf16* Ab    = (__bf16*)alloc((size_t)NTOK * D_MODEL * 2);       // 176-192
    float*  x2    = (float*)alloc((size_t)NTOK * D_MODEL * 4);        // 192-224 f32
    __bf16* gb    = QKb;              // FFN intermediate (64 MB) aliases QKb+Vtg+Ab (dead post O-proj)
    float*  p0    = (float*)(ws);     // W2 split-K partials: slice0 @ 0-32MB, slice1 @ 32-64MB
    float*  p1    = p0 + (size_t)NTOK * D_MODEL;   // = ws + 32MB (aliases tokb..wob, dead by W2)

    // converts
    cvt_f32_bf16<<<(NTOK * D_MODEL) / 1024, 256, 0, stream>>>(tok, tokb);
    cvt_f32_bf16<<<(D_MODEL * D_MODEL) / 1024, 256, 0, stream>>>(Wq, wqb);
    cvt_f32_bf16<<<(D_MODEL * D_MODEL) / 1024, 256, 0, stream>>>(Wk, wkb);
    cvt_f32_bf16<<<(D_MODEL * D_MODEL) / 1024, 256, 0, stream>>>(Wv, wvb);
    cvt_f32_bf16<<<(D_MODEL * D_MODEL) / 1024, 256, 0, stream>>>(Wo, wob);
    cvt_f32_bf16<<<(FF * D_MODEL) / 1024, 256, 0, stream>>>(W1, w1b);
    cvt_f32_bf16<<<(FF * D_MODEL) / 1024, 256, 0, stream>>>(W2, w2b);

    ln_bf16<<<NTOK, 256, 0, stream>>>(x, ln1w, ln1b, hnorm);

    // fused Q+K projection: N=4096 -> 256 blocks (full GPU)
    const int g_qk = (NTOK / 256) * ((2 * D_MODEL) / 256);  // 256
    gemm_bt8<0, 1><<<g_qk, 512, 0, stream>>>(hnorm, wqb, QKb, nullptr, nullptr,
                                             NTOK, 2 * D_MODEL, D_MODEL);
    const int g_sq = (NTOK / 256) * (D_MODEL / 256);        // 128
    gemm_bt8<3, 1><<<g_sq, 512, 0, stream>>>(tokb, wvb, Vtg, nullptr, nullptr,
                                             NTOK, D_MODEL, D_MODEL);

    attn_causal<<<dim3(SEQ / 64, NHEAD, BATCH), 256, 0, stream>>>(QKb, QKb + D_MODEL, Vtg, Ab);

    gemm_bt8<2, 1><<<g_sq, 512, 0, stream>>>(Ab, wob, nullptr, x2, x, NTOK, D_MODEL, D_MODEL);

    ln_bf16<<<NTOK, 256, 0, stream>>>(x2, ln2w, ln2b, hnorm);   // h2

    const int g_ff = (NTOK / 256) * (FF / 256);             // 512
    gemm_bt8<1, 1><<<g_ff, 512, 0, stream>>>(hnorm, w1b, gb, nullptr, nullptr,
                                             NTOK, FF, D_MODEL);
    // W2 with split-K=2 (K=8192): 256 blocks, f32 partials, then fused reduce+residual
    gemm_bt8<4, 2><<<2 * g_sq, 512, 0, stream>>>(gb, w2b, nullptr, p0, nullptr,
                                                 NTOK, D_MODEL, FF);
    add_reduce<<<(NTOK * D_MODEL) / 1024, 256, 0, stream>>>(p0, p1, x2, out);
}

// Round 6
// 760.166 us; speedup vs baseline: 1.5524x; 1.1850x over previous
//
#include <hip/hip_runtime.h>
#include <hip/hip_bf16.h>
#include <math.h>

#define D_MODEL 2048
#define SEQ     2048
#define BATCH   2
#define NTOK    (BATCH*SEQ)      // 4096
#define NHEAD   16
#define HDIM    128
#define FF      8192

typedef float  f32x4  __attribute__((ext_vector_type(4)));
typedef __bf16 bf16x8 __attribute__((ext_vector_type(8)));

__device__ __forceinline__ unsigned short f2bfbits(float f) {
    unsigned u = __builtin_bit_cast(unsigned, f);
    return (unsigned short)((u + 0x7fffu + ((u >> 16) & 1u)) >> 16);
}
__device__ __forceinline__ __bf16 f2bf(float f) {
    unsigned short h = f2bfbits(f);
    return __builtin_bit_cast(__bf16, h);
}

__device__ __forceinline__ void gld_lds16(const void* g, void* l) {
    __builtin_amdgcn_global_load_lds(
        (const __attribute__((address_space(1))) unsigned int*)g,
        (__attribute__((address_space(3))) unsigned int*)l, 16, 0, 0);
}

// ---------------- fused f32 -> bf16 convert for tok + all 6 weights -------------
// virtual concat (elems): tok 8M | Wq 4M | Wk 4M | Wv 4M | Wo 4M | W1 16M | W2 16M
__global__ __launch_bounds__(256) void cvt_all(
        const float* __restrict__ tok, const float* __restrict__ wq,
        const float* __restrict__ wk,  const float* __restrict__ wv,
        const float* __restrict__ wo,  const float* __restrict__ w1,
        const float* __restrict__ w2,
        __bf16* __restrict__ tokb, __bf16* __restrict__ wqb,
        __bf16* __restrict__ wkb,  __bf16* __restrict__ wvb,
        __bf16* __restrict__ wob,  __bf16* __restrict__ w1b,
        __bf16* __restrict__ w2b) {
    const size_t M4 = 4u * 1024 * 1024;
    size_t i = (size_t)blockIdx.x * 1024 + (size_t)threadIdx.x * 4;
    const float* src; __bf16* dst; size_t off;
    if      (i < 2*M4)  { src = tok; dst = tokb; off = i; }
    else if (i < 3*M4)  { src = wq;  dst = wqb;  off = i - 2*M4; }
    else if (i < 4*M4)  { src = wk;  dst = wkb;  off = i - 3*M4; }
    else if (i < 5*M4)  { src = wv;  dst = wvb;  off = i - 4*M4; }
    else if (i < 6*M4)  { src = wo;  dst = wob;  off = i - 5*M4; }
    else if (i < 10*M4) { src = w1;  dst = w1b;  off = i - 6*M4; }
    else                { src = w2;  dst = w2b;  off = i - 10*M4; }
    float4 v = *(const float4*)(src + off);
    ushort4 o;
    o.x = f2bfbits(v.x); o.y = f2bfbits(v.y);
    o.z = f2bfbits(v.z); o.w = f2bfbits(v.w);
    *(ushort4*)((unsigned short*)dst + off) = o;
}

// ---------------- split-K reduce: out = p0 + p1 + resid (f32) ----------------
__global__ __launch_bounds__(256) void add_reduce(
        const float* __restrict__ p0, const float* __restrict__ p1,
        const float* __restrict__ resid, float* __restrict__ out) {
    int i = blockIdx.x * 256 + threadIdx.x;
    float4 a = ((const float4*)p0)[i];
    float4 b = ((const float4*)p1)[i];
    float4 r = ((const float4*)resid)[i];
    float4 o;
    o.x = a.x + b.x + r.x; o.y = a.y + b.y + r.y;
    o.z = a.z + b.z + r.z; o.w = a.w + b.w + r.w;
    ((float4*)out)[i] = o;
}

// ---------------- LayerNorm: f32 in -> bf16 out, one block per row ----------------
__global__ __launch_bounds__(256) void ln_bf16(
        const float* __restrict__ x, const float* __restrict__ w,
        const float* __restrict__ b, __bf16* __restrict__ out) {
    const int row = blockIdx.x;
    const int tid = threadIdx.x;
    const float* xr = x + (size_t)row * D_MODEL;
    float4 v0 = *(const float4*)(xr + tid * 8);
    float4 v1 = *(const float4*)(xr + tid * 8 + 4);
    float va[8] = {v0.x, v0.y, v0.z, v0.w, v1.x, v1.y, v1.z, v1.w};
    float s = 0.f, ss = 0.f;
#pragma unroll
    for (int j = 0; j < 8; ++j) { s += va[j]; ss += va[j] * va[j]; }
#pragma unroll
    for (int m = 32; m; m >>= 1) { s += __shfl_xor(s, m, 64); ss += __shfl_xor(ss, m, 64); }
    __shared__ float red[8];
    const int wid = tid >> 6;
    if ((tid & 63) == 0) { red[wid * 2] = s; red[wid * 2 + 1] = ss; }
    __syncthreads();
    s  = red[0] + red[2] + red[4] + red[6];
    ss = red[1] + red[3] + red[5] + red[7];
    const float mu   = s * (1.0f / D_MODEL);
    const float var  = ss * (1.0f / D_MODEL) - mu * mu;
    const float rstd = rsqrtf(var + 1e-5f);
    const int c = tid * 8;
    ushort4 o0, o1;
    unsigned short ob[8];
#pragma unroll
    for (int j = 0; j < 8; ++j)
        ob[j] = f2bfbits((va[j] - mu) * rstd * w[c + j] + b[c + j]);
    o0.x = ob[0]; o0.y = ob[1]; o0.z = ob[2]; o0.w = ob[3];
    o1.x = ob[4]; o1.y = ob[5]; o1.z = ob[6]; o1.w = ob[7];
    ushort4* op = (ushort4*)(out + (size_t)row * D_MODEL + c);
    op[0] = o0; op[1] = o1;
}

// ---------------- GEMM (256x256, 4-phase, deep prefetch): C = A @ B^T ------------
// 512 threads = 8 waves (2M x 4N), per-wave 128x64 (acc[8][4] of 16x16x32).
// BK=64, LDS = 2 tile-buffers x (A 32KB + B 32KB) = 128 KiB.
// Swizzle (both-sides, rule #21): 16B-chunk col X ^= (r&7)<<4.
//   A 16-lane ds_read_b128 group (rows r..r+15, X fixed) covers all 8 bank
//   slots twice -> 2-way aliasing = free (m136). Bijective per 128B row.
// Staging: ALL 4 half-tiles of tile t+1 issued at t.P1 (buf^1 is dead: its
// last reads drained at t-1.P3 lgkmcnt(0), all waves past t-1 final barrier).
// vmcnt(0) only at t.P4-end => wait distance ~3 phases > HBM latency.
// EPI: 0 bf16 | 1 GELU bf16 | 2 f32+resid | 3 bf16 transposed [b,h,hd,s] | 4 f32 partial
template <int EPI, int SPLITK>
__global__ __launch_bounds__(512, 2) void gemm_bt8(
        const __bf16* __restrict__ A, const __bf16* __restrict__ Bm,
        __bf16* __restrict__ Cb, float* __restrict__ Cf,
        const float* __restrict__ resid, int M, int N, int K) {
    __shared__ __align__(16) __bf16 lds[2][2][256 * 64];
    const int tid = threadIdx.x;
    const int wid = tid >> 6, lane = tid & 63;
    const int l16 = lane & 15, lhi = lane >> 4;
    const int wm = wid >> 2, wn = wid & 3;

    // XCD-aware swizzle (launcher guarantees gridDim.x % 8 == 0)
    int id = blockIdx.x;
    const int cpx = gridDim.x >> 3;
    id = (id & 7) * cpx + (id >> 3);
    const int nbn = N >> 8;
    int slice = 0;
    if (SPLITK == 2) {
        const int nblk = (M >> 8) * nbn;
        slice = id / nblk;
        id -= slice * nblk;
    }
    const int bm = id / nbn, bn = id % nbn;

    const __bf16* Ag = A  + (size_t)bm * 256 * K;
    const __bf16* Bg = Bm + (size_t)bn * 256 * K;
    const int tps = (K >> 6) / SPLITK;       // tiles per slice
    const int t0 = slice * tps, t1 = t0 + tps;

    auto stage = [&](__bf16* region, const __bf16* G, int kt, int half) {
#pragma unroll
        for (int j = 0; j < 2; ++j) {
            int idx = j * 512 + tid;            // 0..1023
            int r128 = idx >> 3;                // row within half
            int Xc = (idx & 7) << 4;            // dest byte col
            int Xs = Xc ^ ((r128 & 7) << 4);    // source col: undo 3-bit swizzle
            gld_lds16((const char*)(G + ((size_t)(half * 128 + r128) * K + kt * 64)) + Xs,
                      (char*)region + half * 16384 + idx * 16);
        }
    };

    f32x4 acc[8][4] = {};
    bf16x8 af0[4][2], af1[4][2], bq0[2][2], bq1[2][2];

    const __bf16* Abase;
    const __bf16* Bbase;
    auto ldA = [&](bf16x8 (&dst)[4][2], int qm) {
#pragma unroll
        for (int i = 0; i < 4; ++i)
#pragma unroll
            for (int ks = 0; ks < 2; ++ks) {
                int r = wm * 128 + (qm * 4 + i) * 16 + l16;
                int X = ks * 64 + lhi * 16;
                dst[i][ks] = *(const bf16x8*)((const char*)Abase + r * 128 +
                                              (X ^ ((r & 7) << 4)));
            }
    };
    auto ldB = [&](bf16x8 (&dst)[2][2], int qn) {
#pragma unroll
        for (int j = 0; j < 2; ++j)
#pragma unroll
            for (int ks = 0; ks < 2; ++ks) {
                int r = wn * 64 + (qn * 2 + j) * 16 + l16;
                int X = ks * 64 + lhi * 16;
                dst[j][ks] = *(const bf16x8*)((const char*)Bbase + r * 128 +
                                              (X ^ ((r & 7) << 4)));
            }
    };
    auto mfmaQ = [&](bf16x8 (&a)[4][2], bf16x8 (&b)[2][2], int mo, int no) {
        __builtin_amdgcn_s_setprio(1);
#pragma unroll
        for (int i = 0; i < 4; ++i)
#pragma unroll
            for (int j = 0; j < 2; ++j)
#pragma unroll
                for (int ks = 0; ks < 2; ++ks)
                    acc[mo + i][no + j] = __builtin_amdgcn_mfma_f32_16x16x32_bf16(
                        a[i][ks], b[j][ks], acc[mo + i][no + j], 0, 0, 0);
        __builtin_amdgcn_s_setprio(0);
    };

    // prologue: tile t0 fully staged, drained
    stage(&lds[0][0][0], Ag, t0, 0); stage(&lds[0][0][0], Ag, t0, 1);
    stage(&lds[0][1][0], Bg, t0, 0); stage(&lds[0][1][0], Bg, t0, 1);
    asm volatile("s_waitcnt vmcnt(0)" ::: "memory");
    __builtin_amdgcn_s_barrier();

    for (int t = t0; t < t1; ++t) {
        const int cur = (t - t0) & 1;
        Abase = &lds[cur][0][0];
        Bbase = &lds[cur][1][0];
        const bool pf = (t + 1 < t1);
        // P1: issue ALL of tile t+1's staging (max wait distance); read q(0,0) frags
        if (pf) {
            stage(&lds[cur ^ 1][0][0], Ag, t + 1, 0);
            stage(&lds[cur ^ 1][0][0], Ag, t + 1, 1);
            stage(&lds[cur ^ 1][1][0], Bg, t + 1, 0);
            stage(&lds[cur ^ 1][1][0], Bg, t + 1, 1);
        }
        ldA(af0, 0); ldB(bq0, 0);
        __builtin_amdgcn_s_barrier();
        asm volatile("s_waitcnt lgkmcnt(0)" ::: "memory");
        __builtin_amdgcn_sched_barrier(0);   // rule #18: pin MFMA below the waitcnt
        mfmaQ(af0, bq0, 0, 0);
        __builtin_amdgcn_s_barrier();
        // P2
        ldB(bq1, 1);
        __builtin_amdgcn_s_barrier();
        asm volatile("s_waitcnt lgkmcnt(0)" ::: "memory");
        __builtin_amdgcn_sched_barrier(0);
        mfmaQ(af0, bq1, 0, 2);
        __builtin_amdgcn_s_barrier();
        // P3
        ldA(af1, 1);
        __builtin_amdgcn_s_barrier();
        asm volatile("s_waitcnt lgkmcnt(0)" ::: "memory");
        __builtin_amdgcn_sched_barrier(0);
        mfmaQ(af1, bq0, 4, 0);
        __builtin_amdgcn_s_barrier();
        // P4: register-only MFMA, then drain next tile's loads (issued 3 phases ago)
        mfmaQ(af1, bq1, 4, 2);
        if (pf) asm volatile("s_waitcnt vmcnt(0)" ::: "memory");
        __builtin_amdgcn_s_barrier();
    }

#pragma unroll
    for (int m = 0; m < 8; ++m) {
        const int row = bm * 256 + wm * 128 + m * 16 + lhi * 4;
#pragma unroll
        for (int n = 0; n < 4; ++n) {
            const int col = bn * 256 + wn * 64 + n * 16 + l16;
            if (EPI == 3) {
                const int h = col >> 7, hd = col & 127;
                const size_t obase =
                    ((((size_t)(row >> 11) * NHEAD + h) * HDIM + hd) << 11) + (row & 2047);
                ushort4 o;
                o.x = f2bfbits(acc[m][n][0]); o.y = f2bfbits(acc[m][n][1]);
                o.z = f2bfbits(acc[m][n][2]); o.w = f2bfbits(acc[m][n][3]);
                *(ushort4*)((unsigned short*)Cb + obase) = o;
            } else {
#pragma unroll
                for (int r = 0; r < 4; ++r) {
                    float v = acc[m][n][r];
                    size_t off = (size_t)(row + r) * N + col;
                    if (EPI == 0) {
                        Cb[off] = f2bf(v);
                    } else if (EPI == 1) {
                        Cb[off] = f2bf(0.5f * v * (1.0f + erff(v * 0.70710678118654752f)));
                    } else if (EPI == 2) {
                        Cf[off] = v + resid[off];
                    } else {  // EPI == 4: f32 partial per slice
                        Cf[(size_t)slice * M * N + off] = v;
                    }
                }
            }
        }
    }
}

// ---------------- Causal flash attention ----------------
// Q,K come from the fused QK buffer [4096 tok][4096] (Q cols 0..2047, K cols
// 2048..4095 passed as base+2048): row stride LDQK=4096. V pre-transposed
// [b,h,d,s]. K/V staged via global_load_lds with XOR-swizzled SOURCE.
#define LDQK 4096
__global__ __launch_bounds__(256) void attn_causal(
        const __bf16* __restrict__ Q, const __bf16* __restrict__ K,
        const __bf16* __restrict__ Vt, __bf16* __restrict__ O) {
    const int qt = gridDim.x - 1 - blockIdx.x;   // heavy blocks first
    const int h = blockIdx.y, bb = blockIdx.z;
    const int tid = threadIdx.x, wid = tid >> 6, lane = tid & 63;
    const int l16 = lane & 15, lhi = lane >> 4;
    __shared__ __align__(16) __bf16 Ks[64 * 128];   // [tok][d], chunk-swizzled
    __shared__ __align__(16) __bf16 Vs[128 * 64];   // [d][tok], chunk-swizzled
    __shared__ __align__(16) __bf16 Pl[4][16 * 72]; // per-wave P [q][tok], pad 72

    const size_t qkbase = ((size_t)bb * SEQ) * LDQK + (size_t)h * HDIM;
    const size_t obase  = ((size_t)bb * SEQ) * D_MODEL + (size_t)h * HDIM;
    const size_t vtbase = (((size_t)bb * NHEAD + h) * HDIM) << 11;  // [d][s]
    const int q0 = qt * 64 + wid * 16;

    bf16x8 qf[4];
#pragma unroll
    for (int ks = 0; ks < 4; ++ks)
        qf[ks] = *(const bf16x8*)(Q + qkbase + (size_t)(q0 + l16) * LDQK + ks * 32 + lhi * 8);

    f32x4 accO[8] = {};
    float m_run[4], l_run[4];
#pragma unroll
    for (int r = 0; r < 4; ++r) { m_run[r] = -1e30f; l_run[r] = 0.f; }

    const float scale2 = 0.08838834764831845f * 1.4426950408889634f;

    for (int kt = 0; kt <= qt; ++kt) {
#pragma unroll
        for (int i = 0; i < 4; ++i) {
            int idx = i * 256 + tid;
            int row = idx >> 4, c8 = idx & 15;
            int c8s = c8 ^ (row & 7);
            gld_lds16(K + qkbase + (size_t)(kt * 64 + row) * LDQK + c8s * 8, Ks + idx * 8);
        }
#pragma unroll
        for (int i = 0; i < 4; ++i) {
            int idx = i * 256 + tid;
            int row = idx >> 3, c8 = idx & 7;
            int c8s = c8 ^ (row & 7);
            gld_lds16(Vt + vtbase + (size_t)row * SEQ + kt * 64 + c8s * 8, Vs + idx * 8);
        }
        __syncthreads();

        f32x4 s[4] = {};
        __builtin_amdgcn_s_setprio(1);
#pragma unroll
        for (int nb = 0; nb < 4; ++nb) {
            const int tok = nb * 16 + l16;
#pragma unroll
            for (int ks = 0; ks < 4; ++ks) {
                int co = (ks * 64 + lhi * 16) ^ ((tok & 7) << 4);
                bf16x8 kf = *(const bf16x8*)((const char*)Ks + tok * 256 + co);
                s[nb] = __builtin_amdgcn_mfma_f32_16x16x32_bf16(qf[ks], kf, s[nb], 0, 0, 0);
            }
        }
        __builtin_amdgcn_s_setprio(0);
        const bool diag = (kt == qt);
#pragma unroll
        for (int nb = 0; nb < 4; ++nb)
#pragma unroll
            for (int r = 0; r < 4; ++r) {
                float sv = s[nb][r] * scale2;
                if (diag && (nb * 16 + l16) > (wid * 16 + lhi * 4 + r)) sv = -1e30f;
                s[nb][r] = sv;
            }
        float alpha[4];
#pragma unroll
        for (int r = 0; r < 4; ++r) {
            float mx = fmaxf(fmaxf(s[0][r], s[1][r]), fmaxf(s[2][r], s[3][r]));
#pragma unroll
            for (int m = 8; m; m >>= 1) mx = fmaxf(mx, __shfl_xor(mx, m, 64));
            float mnew = fmaxf(m_run[r], mx);
            alpha[r] = exp2f(m_run[r] - mnew);
            float rs = 0.f;
#pragma unroll
            for (int nb = 0; nb < 4; ++nb) {
                float p = exp2f(s[nb][r] - mnew);
                s[nb][r] = p;
                rs += p;
            }
#pragma unroll
            for (int m = 8; m; m >>= 1) rs += __shfl_xor(rs, m, 64);
            l_run[r] = l_run[r] * alpha[r] + rs;
            m_run[r] = mnew;
        }
#pragma unroll
        for (int d8 = 0; d8 < 8; ++d8)
#pragma unroll
            for (int r = 0; r < 4; ++r) accO[d8][r] *= alpha[r];
#pragma unroll
        for (int nb = 0; nb < 4; ++nb)
#pragma unroll
            for (int r = 0; r < 4; ++r)
                Pl[wid][(lhi * 4 + r) * 72 + nb * 16 + l16] = f2bf(s[nb][r]);
        __builtin_amdgcn_s_setprio(1);
#pragma unroll
        for (int ks2 = 0; ks2 < 2; ++ks2) {
            bf16x8 pa = *(const bf16x8*)(&Pl[wid][l16 * 72 + ks2 * 32 + lhi * 8]);
#pragma unroll
            for (int d8 = 0; d8 < 8; ++d8) {
                const int d = d8 * 16 + l16;
                const int co = ((ks2 * 4 + lhi) ^ (d & 7)) << 4;
                bf16x8 vf = *(const bf16x8*)((const char*)Vs + d * 128 + co);
                accO[d8] = __builtin_amdgcn_mfma_f32_16x16x32_bf16(pa, vf, accO[d8], 0, 0, 0);
            }
        }
        __builtin_amdgcn_s_setprio(0);
        __syncthreads();
    }

#pragma unroll
    for (int d8 = 0; d8 < 8; ++d8)
#pragma unroll
        for (int r = 0; r < 4; ++r) {
            float o = accO[d8][r] / l_run[r];
            O[obase + (size_t)(q0 + lhi * 4 + r) * D_MODEL + d8 * 16 + l16] = f2bf(o);
        }
}

// ---------------- host launcher ----------------
extern "C" void kernel_launch(void* const* d_in, const int* in_sizes, int n_in,
                              void* d_out, int out_size, void* d_ws, size_t ws_size,
                              hipStream_t stream) {
    const float* x    = (const float*)d_in[0];
    const float* tok  = (const float*)d_in[1];
    const float* Wq   = (const float*)d_in[2];
    const float* Wk   = (const float*)d_in[3];
    const float* Wv   = (const float*)d_in[4];
    const float* Wo   = (const float*)d_in[5];
    const float* W1   = (const float*)d_in[6];
    const float* W2   = (const float*)d_in[7];
    const float* ln1w = (const float*)d_in[8];
    const float* ln1b = (const float*)d_in[9];
    const float* ln2w = (const float*)d_in[10];
    const float* ln2b = (const float*)d_in[11];
    float* out = (float*)d_out;

    char* ws = (char*)d_ws;
    size_t off = 0;
    auto alloc = [&](size_t bytes) { void* p = ws + off; off += bytes; return p; };
    __bf16* tokb  = (__bf16*)alloc((size_t)NTOK * D_MODEL * 2);       //   0-16 MB
    __bf16* hnorm = (__bf16*)alloc((size_t)NTOK * D_MODEL * 2);       //  16-32
    __bf16* wqb   = (__bf16*)alloc((size_t)D_MODEL * D_MODEL * 2);    //  32-40 (wq|wk adjacent = fused QK weight)
    __bf16* wkb   = (__bf16*)alloc((size_t)D_MODEL * D_MODEL * 2);    //  40-48
    __bf16* wvb   = (__bf16*)alloc((size_t)D_MODEL * D_MODEL * 2);    //  48-56
    __bf16* wob   = (__bf16*)alloc((size_t)D_MODEL * D_MODEL * 2);    //  56-64
    __bf16* w1b   = (__bf16*)alloc((size_t)FF * D_MODEL * 2);         //  64-96
    __bf16* w2b   = (__bf16*)alloc((size_t)D_MODEL * FF * 2);         //  96-128
    __bf16* QKb   = (__bf16*)alloc((size_t)NTOK * 2 * D_MODEL * 2);   // 128-160 (fused [tok][4096])
    __bf16* Vtg   = (__bf16*)alloc((size_t)NTOK * D_MODEL * 2);       // 160-176 V^T [b,h,d,s]
    __bf16* Ab    = (__bf16*)alloc((size_t)NTOK * D_MODEL * 2);       // 176-192
    float*  x2    = (float*)alloc((size_t)NTOK * D_MODEL * 4);        // 192-224 f32
    __bf16* gb    = QKb;              // FFN intermediate (64 MB) aliases QKb+Vtg+Ab (dead post O-proj)
    float*  p0    = (float*)(ws);     // W2 split-K partials: slice0 @ 0-32MB, slice1 @ 32-64MB
    float*  p1    = p0 + (size_t)NTOK * D_MODEL;   // = ws + 32MB (aliases tokb..wob, dead by W2)

    // fused converts: (8+4*4+16+16)M elems / 1024 per block
    cvt_all<<<56 * 1024, 256, 0, stream>>>(tok, Wq, Wk, Wv, Wo, W1, W2,
                                           tokb, wqb, wkb, wvb, wob, w1b, w2b);

    ln_bf16<<<NTOK, 256, 0, stream>>>(x, ln1w, ln1b, hnorm);

    // fused Q+K projection: N=4096 -> 256 blocks (full GPU)
    const int g_qk = (NTOK / 256) * ((2 * D_MODEL) / 256);  // 256
    gemm_bt8<0, 1><<<g_qk, 512, 0, stream>>>(hnorm, wqb, QKb, nullptr, nullptr,
                                             NTOK, 2 * D_MODEL, D_MODEL);
    const int g_sq = (NTOK / 256) * (D_MODEL / 256);        // 128
    gemm_bt8<3, 1><<<g_sq, 512, 0, stream>>>(tokb, wvb, Vtg, nullptr, nullptr,
                                             NTOK, D_MODEL, D_MODEL);

    attn_causal<<<dim3(SEQ / 64, NHEAD, BATCH), 256, 0, stream>>>(QKb, QKb + D_MODEL, Vtg, Ab);

    gemm_bt8<2, 1><<<g_sq, 512, 0, stream>>>(Ab, wob, nullptr, x2, x, NTOK, D_MODEL, D_MODEL);

    ln_bf16<<<NTOK, 256, 0, stream>>>(x2, ln2w, ln2b, hnorm);   // h2

    const int g_ff = (NTOK / 256) * (FF / 256);             // 512
    gemm_bt8<1, 1><<<g_ff, 512, 0, stream>>>(hnorm, w1b, gb, nullptr, nullptr,
                                             NTOK, FF, D_MODEL);
    // W2 with split-K=2 (K=8192): 256 blocks, f32 partials, then fused reduce+residual
    gemm_bt8<4, 2><<<2 * g_sq, 512, 0, stream>>>(gb, w2b, nullptr, p0, nullptr,
                                                 NTOK, D_MODEL, FF);
    add_reduce<<<(NTOK * D_MODEL) / 1024, 256, 0, stream>>>(p0, p1, x2, out);
}

// Round 7
// 721.917 us; speedup vs baseline: 1.6346x; 1.0530x over previous
//
#include <hip/hip_runtime.h>
#include <hip/hip_bf16.h>
#include <math.h>

#define D_MODEL 2048
#define SEQ     2048
#define BATCH   2
#define NTOK    (BATCH*SEQ)      // 4096
#define NHEAD   16
#define HDIM    128
#define FF      8192

typedef float  f32x4  __attribute__((ext_vector_type(4)));
typedef __bf16 bf16x8 __attribute__((ext_vector_type(8)));

__device__ __forceinline__ unsigned short f2bfbits(float f) {
    unsigned u = __builtin_bit_cast(unsigned, f);
    return (unsigned short)((u + 0x7fffu + ((u >> 16) & 1u)) >> 16);
}
__device__ __forceinline__ __bf16 f2bf(float f) {
    unsigned short h = f2bfbits(f);
    return __builtin_bit_cast(__bf16, h);
}

__device__ __forceinline__ void gld_lds16(const void* g, void* l) {
    __builtin_amdgcn_global_load_lds(
        (const __attribute__((address_space(1))) unsigned int*)g,
        (__attribute__((address_space(3))) unsigned int*)l, 16, 0, 0);
}

// ---------------- fused f32 -> bf16 convert for tok + all 6 weights -------------
// virtual concat (elems): tok 8M | Wq 4M | Wk 4M | Wv 4M | Wo 4M | W1 16M | W2 16M
__global__ __launch_bounds__(256) void cvt_all(
        const float* __restrict__ tok, const float* __restrict__ wq,
        const float* __restrict__ wk,  const float* __restrict__ wv,
        const float* __restrict__ wo,  const float* __restrict__ w1,
        const float* __restrict__ w2,
        __bf16* __restrict__ tokb, __bf16* __restrict__ wqb,
        __bf16* __restrict__ wkb,  __bf16* __restrict__ wvb,
        __bf16* __restrict__ wob,  __bf16* __restrict__ w1b,
        __bf16* __restrict__ w2b) {
    const size_t M4 = 4u * 1024 * 1024;
    size_t i = (size_t)blockIdx.x * 1024 + (size_t)threadIdx.x * 4;
    const float* src; __bf16* dst; size_t off;
    if      (i < 2*M4)  { src = tok; dst = tokb; off = i; }
    else if (i < 3*M4)  { src = wq;  dst = wqb;  off = i - 2*M4; }
    else if (i < 4*M4)  { src = wk;  dst = wkb;  off = i - 3*M4; }
    else if (i < 5*M4)  { src = wv;  dst = wvb;  off = i - 4*M4; }
    else if (i < 6*M4)  { src = wo;  dst = wob;  off = i - 5*M4; }
    else if (i < 10*M4) { src = w1;  dst = w1b;  off = i - 6*M4; }
    else                { src = w2;  dst = w2b;  off = i - 10*M4; }
    float4 v = *(const float4*)(src + off);
    ushort4 o;
    o.x = f2bfbits(v.x); o.y = f2bfbits(v.y);
    o.z = f2bfbits(v.z); o.w = f2bfbits(v.w);
    *(ushort4*)((unsigned short*)dst + off) = o;
}

// ---------------- split-K reduce: out = p0 + p1 + resid (f32) ----------------
__global__ __launch_bounds__(256) void add_reduce(
        const float* __restrict__ p0, const float* __restrict__ p1,
        const float* __restrict__ resid, float* __restrict__ out) {
    int i = blockIdx.x * 256 + threadIdx.x;
    float4 a = ((const float4*)p0)[i];
    float4 b = ((const float4*)p1)[i];
    float4 r = ((const float4*)resid)[i];
    float4 o;
    o.x = a.x + b.x + r.x; o.y = a.y + b.y + r.y;
    o.z = a.z + b.z + r.z; o.w = a.w + b.w + r.w;
    ((float4*)out)[i] = o;
}

// ---------------- LayerNorm: f32 in -> bf16 out, one block per row ----------------
__global__ __launch_bounds__(256) void ln_bf16(
        const float* __restrict__ x, const float* __restrict__ w,
        const float* __restrict__ b, __bf16* __restrict__ out) {
    const int row = blockIdx.x;
    const int tid = threadIdx.x;
    const float* xr = x + (size_t)row * D_MODEL;
    float4 v0 = *(const float4*)(xr + tid * 8);
    float4 v1 = *(const float4*)(xr + tid * 8 + 4);
    float va[8] = {v0.x, v0.y, v0.z, v0.w, v1.x, v1.y, v1.z, v1.w};
    float s = 0.f, ss = 0.f;
#pragma unroll
    for (int j = 0; j < 8; ++j) { s += va[j]; ss += va[j] * va[j]; }
#pragma unroll
    for (int m = 32; m; m >>= 1) { s += __shfl_xor(s, m, 64); ss += __shfl_xor(ss, m, 64); }
    __shared__ float red[8];
    const int wid = tid >> 6;
    if ((tid & 63) == 0) { red[wid * 2] = s; red[wid * 2 + 1] = ss; }
    __syncthreads();
    s  = red[0] + red[2] + red[4] + red[6];
    ss = red[1] + red[3] + red[5] + red[7];
    const float mu   = s * (1.0f / D_MODEL);
    const float var  = ss * (1.0f / D_MODEL) - mu * mu;
    const float rstd = rsqrtf(var + 1e-5f);
    const int c = tid * 8;
    ushort4 o0, o1;
    unsigned short ob[8];
#pragma unroll
    for (int j = 0; j < 8; ++j)
        ob[j] = f2bfbits((va[j] - mu) * rstd * w[c + j] + b[c + j]);
    o0.x = ob[0]; o0.y = ob[1]; o0.z = ob[2]; o0.w = ob[3];
    o1.x = ob[4]; o1.y = ob[5]; o1.z = ob[6]; o1.w = ob[7];
    ushort4* op = (ushort4*)(out + (size_t)row * D_MODEL + c);
    op[0] = o0; op[1] = o1;
}

// ---------------- GEMM (256x256, 4-phase, deep prefetch): C = A @ B^T ------------
// 512 threads = 8 waves (2M x 4N), per-wave 128x64 (acc[8][4] of 16x16x32).
// BK=64, LDS = 2 tile-buffers x (A 32KB + B 32KB) = 128 KiB.
// Swizzle (both-sides, rule #21): 16B-chunk col X ^= (r&7)<<4 -> 2-way = free.
// Staging: ALL 4 half-tiles of tile t+1 issued at t.P1; vmcnt(0) only at t.P4-end.
// EPI: 0 bf16 | 1 GELU bf16 | 2 f32+resid | 3 bf16 transposed [b,h,hd,s] | 4 f32 partial
template <int EPI, int SPLITK>
__global__ __launch_bounds__(512, 2) void gemm_bt8(
        const __bf16* __restrict__ A, const __bf16* __restrict__ Bm,
        __bf16* __restrict__ Cb, float* __restrict__ Cf,
        const float* __restrict__ resid, int M, int N, int K) {
    __shared__ __align__(16) __bf16 lds[2][2][256 * 64];
    const int tid = threadIdx.x;
    const int wid = tid >> 6, lane = tid & 63;
    const int l16 = lane & 15, lhi = lane >> 4;
    const int wm = wid >> 2, wn = wid & 3;

    // XCD-aware swizzle (launcher guarantees gridDim.x % 8 == 0)
    int id = blockIdx.x;
    const int cpx = gridDim.x >> 3;
    id = (id & 7) * cpx + (id >> 3);
    const int nbn = N >> 8;
    int slice = 0;
    if (SPLITK == 2) {
        const int nblk = (M >> 8) * nbn;
        slice = id / nblk;
        id -= slice * nblk;
    }
    const int bm = id / nbn, bn = id % nbn;

    const __bf16* Ag = A  + (size_t)bm * 256 * K;
    const __bf16* Bg = Bm + (size_t)bn * 256 * K;
    const int tps = (K >> 6) / SPLITK;       // tiles per slice
    const int t0 = slice * tps, t1 = t0 + tps;

    auto stage = [&](__bf16* region, const __bf16* G, int kt, int half) {
#pragma unroll
        for (int j = 0; j < 2; ++j) {
            int idx = j * 512 + tid;            // 0..1023
            int r128 = idx >> 3;                // row within half
            int Xc = (idx & 7) << 4;            // dest byte col
            int Xs = Xc ^ ((r128 & 7) << 4);    // source col: undo 3-bit swizzle
            gld_lds16((const char*)(G + ((size_t)(half * 128 + r128) * K + kt * 64)) + Xs,
                      (char*)region + half * 16384 + idx * 16);
        }
    };

    f32x4 acc[8][4] = {};
    bf16x8 af0[4][2], af1[4][2], bq0[2][2], bq1[2][2];

    const __bf16* Abase;
    const __bf16* Bbase;
    auto ldA = [&](bf16x8 (&dst)[4][2], int qm) {
#pragma unroll
        for (int i = 0; i < 4; ++i)
#pragma unroll
            for (int ks = 0; ks < 2; ++ks) {
                int r = wm * 128 + (qm * 4 + i) * 16 + l16;
                int X = ks * 64 + lhi * 16;
                dst[i][ks] = *(const bf16x8*)((const char*)Abase + r * 128 +
                                              (X ^ ((r & 7) << 4)));
            }
    };
    auto ldB = [&](bf16x8 (&dst)[2][2], int qn) {
#pragma unroll
        for (int j = 0; j < 2; ++j)
#pragma unroll
            for (int ks = 0; ks < 2; ++ks) {
                int r = wn * 64 + (qn * 2 + j) * 16 + l16;
                int X = ks * 64 + lhi * 16;
                dst[j][ks] = *(const bf16x8*)((const char*)Bbase + r * 128 +
                                              (X ^ ((r & 7) << 4)));
            }
    };
    auto mfmaQ = [&](bf16x8 (&a)[4][2], bf16x8 (&b)[2][2], int mo, int no) {
        __builtin_amdgcn_s_setprio(1);
#pragma unroll
        for (int i = 0; i < 4; ++i)
#pragma unroll
            for (int j = 0; j < 2; ++j)
#pragma unroll
                for (int ks = 0; ks < 2; ++ks)
                    acc[mo + i][no + j] = __builtin_amdgcn_mfma_f32_16x16x32_bf16(
                        a[i][ks], b[j][ks], acc[mo + i][no + j], 0, 0, 0);
        __builtin_amdgcn_s_setprio(0);
    };

    // prologue: tile t0 fully staged, drained
    stage(&lds[0][0][0], Ag, t0, 0); stage(&lds[0][0][0], Ag, t0, 1);
    stage(&lds[0][1][0], Bg, t0, 0); stage(&lds[0][1][0], Bg, t0, 1);
    asm volatile("s_waitcnt vmcnt(0)" ::: "memory");
    __builtin_amdgcn_s_barrier();

    for (int t = t0; t < t1; ++t) {
        const int cur = (t - t0) & 1;
        Abase = &lds[cur][0][0];
        Bbase = &lds[cur][1][0];
        const bool pf = (t + 1 < t1);
        // P1: issue ALL of tile t+1's staging (max wait distance); read q(0,0) frags
        if (pf) {
            stage(&lds[cur ^ 1][0][0], Ag, t + 1, 0);
            stage(&lds[cur ^ 1][0][0], Ag, t + 1, 1);
            stage(&lds[cur ^ 1][1][0], Bg, t + 1, 0);
            stage(&lds[cur ^ 1][1][0], Bg, t + 1, 1);
        }
        ldA(af0, 0); ldB(bq0, 0);
        __builtin_amdgcn_s_barrier();
        asm volatile("s_waitcnt lgkmcnt(0)" ::: "memory");
        __builtin_amdgcn_sched_barrier(0);   // rule #18: pin MFMA below the waitcnt
        mfmaQ(af0, bq0, 0, 0);
        __builtin_amdgcn_s_barrier();
        // P2
        ldB(bq1, 1);
        __builtin_amdgcn_s_barrier();
        asm volatile("s_waitcnt lgkmcnt(0)" ::: "memory");
        __builtin_amdgcn_sched_barrier(0);
        mfmaQ(af0, bq1, 0, 2);
        __builtin_amdgcn_s_barrier();
        // P3
        ldA(af1, 1);
        __builtin_amdgcn_s_barrier();
        asm volatile("s_waitcnt lgkmcnt(0)" ::: "memory");
        __builtin_amdgcn_sched_barrier(0);
        mfmaQ(af1, bq0, 4, 0);
        __builtin_amdgcn_s_barrier();
        // P4: register-only MFMA, then drain next tile's loads (issued 3 phases ago)
        mfmaQ(af1, bq1, 4, 2);
        if (pf) asm volatile("s_waitcnt vmcnt(0)" ::: "memory");
        __builtin_amdgcn_s_barrier();
    }

#pragma unroll
    for (int m = 0; m < 8; ++m) {
        const int row = bm * 256 + wm * 128 + m * 16 + lhi * 4;
#pragma unroll
        for (int n = 0; n < 4; ++n) {
            const int col = bn * 256 + wn * 64 + n * 16 + l16;
            if (EPI == 3) {
                const int h = col >> 7, hd = col & 127;
                const size_t obase =
                    ((((size_t)(row >> 11) * NHEAD + h) * HDIM + hd) << 11) + (row & 2047);
                ushort4 o;
                o.x = f2bfbits(acc[m][n][0]); o.y = f2bfbits(acc[m][n][1]);
                o.z = f2bfbits(acc[m][n][2]); o.w = f2bfbits(acc[m][n][3]);
                *(ushort4*)((unsigned short*)Cb + obase) = o;
            } else {
#pragma unroll
                for (int r = 0; r < 4; ++r) {
                    float v = acc[m][n][r];
                    size_t off = (size_t)(row + r) * N + col;
                    if (EPI == 0) {
                        Cb[off] = f2bf(v);
                    } else if (EPI == 1) {
                        Cb[off] = f2bf(0.5f * v * (1.0f + erff(v * 0.70710678118654752f)));
                    } else if (EPI == 2) {
                        Cf[off] = v + resid[off];
                    } else {  // EPI == 4: f32 partial per slice
                        Cf[(size_t)slice * M * N + off] = v;
                    }
                }
            }
        }
    }
}

// ---------------- Causal flash attention (v2: 8 waves, QBLK=128, pipelined) -------
// grid (S/128, H, B) = 512 blocks x 512 thr. Wave w owns q rows qt*128+w*16..+16.
// K double-buffered: K(kt+1) issued at tile top (one full tile of latency hiding).
// V single buffer, issued BEFORE K so mid-tile vmcnt(2) waits V only; K's 2 loads
// stay in flight across the barrier (counted vmcnt — never drain mid-loop).
// Raw s_barrier + explicit waitcnt (NOT __syncthreads, which drains vmcnt).
// LDS 66.6KB -> 2 blocks/CU co-resident (16 waves/CU).
#define LDQK 4096
__global__ __launch_bounds__(512) void attn_causal(
        const __bf16* __restrict__ Q, const __bf16* __restrict__ K,
        const __bf16* __restrict__ Vt, __bf16* __restrict__ O) {
    const int qt = gridDim.x - 1 - blockIdx.x;   // heavy blocks first
    const int h = blockIdx.y, bb = blockIdx.z;
    const int tid = threadIdx.x, wid = tid >> 6, lane = tid & 63;
    const int l16 = lane & 15, lhi = lane >> 4;
    __shared__ __align__(16) __bf16 Ks[2][64 * 128]; // [tok][d], chunk-swizzled, dbuf
    __shared__ __align__(16) __bf16 Vs[128 * 64];    // [d][tok], chunk-swizzled
    __shared__ __align__(16) __bf16 Pl[8][16 * 72];  // per-wave P [q][tok], pad 72

    const size_t qkbase = ((size_t)bb * SEQ) * LDQK + (size_t)h * HDIM;
    const size_t obase  = ((size_t)bb * SEQ) * D_MODEL + (size_t)h * HDIM;
    const size_t vtbase = (((size_t)bb * NHEAD + h) * HDIM) << 11;  // [d][s]
    const int q0 = qt * 128 + wid * 16;

    bf16x8 qf[4];
#pragma unroll
    for (int ks = 0; ks < 4; ++ks)
        qf[ks] = *(const bf16x8*)(Q + qkbase + (size_t)(q0 + l16) * LDQK + ks * 32 + lhi * 8);

    // stage K tile kt into Ks[buf]: 1024 chunks / 512 thr = 2 gld each
    auto stageK = [&](int kt, int buf) {
#pragma unroll
        for (int j = 0; j < 2; ++j) {
            int idx = j * 512 + tid;
            int row = idx >> 4, c8 = idx & 15;
            int c8s = c8 ^ (row & 7);
            gld_lds16(K + qkbase + (size_t)(kt * 64 + row) * LDQK + c8s * 8,
                      &Ks[buf][0] + idx * 8);
        }
    };
    auto stageV = [&](int kt) {
#pragma unroll
        for (int j = 0; j < 2; ++j) {
            int idx = j * 512 + tid;
            int row = idx >> 3, c8 = idx & 7;
            int c8s = c8 ^ (row & 7);
            gld_lds16(Vt + vtbase + (size_t)row * SEQ + kt * 64 + c8s * 8, Vs + idx * 8);
        }
    };

    f32x4 accO[8] = {};
    float m_run[4], l_run[4];
#pragma unroll
    for (int r = 0; r < 4; ++r) { m_run[r] = -1e30f; l_run[r] = 0.f; }

    const float scale2 = 0.08838834764831845f * 1.4426950408889634f;
    const int NKT = (qt + 1) * 2;   // KV tiles of 64 covering q rows < (qt+1)*128

    stageK(0, 0);
    asm volatile("s_waitcnt vmcnt(0)" ::: "memory");
    __builtin_amdgcn_s_barrier();
    __builtin_amdgcn_sched_barrier(0);

    for (int kt = 0; kt < NKT; ++kt) {
        const int cb = kt & 1;
        const bool pf = (kt + 1 < NKT);
        // issue V(kt) FIRST, then K(kt+1): vmcnt(2) later waits V, leaves K flying
        stageV(kt);
        if (pf) stageK(kt + 1, cb ^ 1);

        // QK^T on Ks[cb]
        f32x4 s[4] = {};
        __builtin_amdgcn_s_setprio(1);
#pragma unroll
        for (int nb = 0; nb < 4; ++nb) {
            const int tok = nb * 16 + l16;
#pragma unroll
            for (int ks = 0; ks < 4; ++ks) {
                int co = (ks * 64 + lhi * 16) ^ ((tok & 7) << 4);
                bf16x8 kf = *(const bf16x8*)((const char*)&Ks[cb][0] + tok * 256 + co);
                s[nb] = __builtin_amdgcn_mfma_f32_16x16x32_bf16(qf[ks], kf, s[nb], 0, 0, 0);
            }
        }
        __builtin_amdgcn_s_setprio(0);

        // scale + causal mask (wave-uniform branch; fully-masked tiles are no-ops)
        if (((kt + 1) << 6) > q0) {
#pragma unroll
            for (int nb = 0; nb < 4; ++nb)
#pragma unroll
                for (int r = 0; r < 4; ++r) {
                    float sv = s[nb][r] * scale2;
                    if ((kt * 64 + nb * 16 + l16) > (q0 + lhi * 4 + r)) sv = -1e30f;
                    s[nb][r] = sv;
                }
        } else {
#pragma unroll
            for (int nb = 0; nb < 4; ++nb)
#pragma unroll
                for (int r = 0; r < 4; ++r) s[nb][r] *= scale2;
        }

        // online softmax (base-2), row-reduce over 16-lane tok groups
        float alpha[4];
#pragma unroll
        for (int r = 0; r < 4; ++r) {
            float mx = fmaxf(fmaxf(s[0][r], s[1][r]), fmaxf(s[2][r], s[3][r]));
#pragma unroll
            for (int m = 8; m; m >>= 1) mx = fmaxf(mx, __shfl_xor(mx, m, 64));
            float mnew = fmaxf(m_run[r], mx);
            alpha[r] = exp2f(m_run[r] - mnew);
            float rs = 0.f;
#pragma unroll
            for (int nb = 0; nb < 4; ++nb) {
                float p = exp2f(s[nb][r] - mnew);
                s[nb][r] = p;
                rs += p;
            }
#pragma unroll
            for (int m = 8; m; m >>= 1) rs += __shfl_xor(rs, m, 64);
            l_run[r] = l_run[r] * alpha[r] + rs;
            m_run[r] = mnew;
        }
#pragma unroll
        for (int d8 = 0; d8 < 8; ++d8)
#pragma unroll
            for (int r = 0; r < 4; ++r) accO[d8][r] *= alpha[r];
        // P -> per-wave LDS in A-fragment layout [q][tok]
#pragma unroll
        for (int nb = 0; nb < 4; ++nb)
#pragma unroll
            for (int r = 0; r < 4; ++r)
                Pl[wid][(lhi * 4 + r) * 72 + nb * 16 + l16] = f2bf(s[nb][r]);

        // wait V landed (K prefetch stays outstanding), all-wave barrier, then PV
        if (pf) asm volatile("s_waitcnt vmcnt(2)" ::: "memory");
        else    asm volatile("s_waitcnt vmcnt(0)" ::: "memory");
        __builtin_amdgcn_s_barrier();
        __builtin_amdgcn_sched_barrier(0);

        __builtin_amdgcn_s_setprio(1);
#pragma unroll
        for (int ks2 = 0; ks2 < 2; ++ks2) {
            bf16x8 pa = *(const bf16x8*)(&Pl[wid][l16 * 72 + ks2 * 32 + lhi * 8]);
#pragma unroll
            for (int d8 = 0; d8 < 8; ++d8) {
                const int d = d8 * 16 + l16;
                const int co = ((ks2 * 4 + lhi) ^ (d & 7)) << 4;
                bf16x8 vf = *(const bf16x8*)((const char*)Vs + d * 128 + co);
                accO[d8] = __builtin_amdgcn_mfma_f32_16x16x32_bf16(pa, vf, accO[d8], 0, 0, 0);
            }
        }
        __builtin_amdgcn_s_setprio(0);

        // end of tile: K(kt+1) must be fully landed before any wave's next QK
        asm volatile("s_waitcnt vmcnt(0)" ::: "memory");
        __builtin_amdgcn_s_barrier();
        __builtin_amdgcn_sched_barrier(0);
    }

#pragma unroll
    for (int d8 = 0; d8 < 8; ++d8)
#pragma unroll
        for (int r = 0; r < 4; ++r) {
            float o = accO[d8][r] / l_run[r];
            O[obase + (size_t)(q0 + lhi * 4 + r) * D_MODEL + d8 * 16 + l16] = f2bf(o);
        }
}

// ---------------- host launcher ----------------
extern "C" void kernel_launch(void* const* d_in, const int* in_sizes, int n_in,
                              void* d_out, int out_size, void* d_ws, size_t ws_size,
                              hipStream_t stream) {
    const float* x    = (const float*)d_in[0];
    const float* tok  = (const float*)d_in[1];
    const float* Wq   = (const float*)d_in[2];
    const float* Wk   = (const float*)d_in[3];
    const float* Wv   = (const float*)d_in[4];
    const float* Wo   = (const float*)d_in[5];
    const float* W1   = (const float*)d_in[6];
    const float* W2   = (const float*)d_in[7];
    const float* ln1w = (const float*)d_in[8];
    const float* ln1b = (const float*)d_in[9];
    const float* ln2w = (const float*)d_in[10];
    const float* ln2b = (const float*)d_in[11];
    float* out = (float*)d_out;

    char* ws = (char*)d_ws;
    size_t off = 0;
    auto alloc = [&](size_t bytes) { void* p = ws + off; off += bytes; return p; };
    __bf16* tokb  = (__bf16*)alloc((size_t)NTOK * D_MODEL * 2);       //   0-16 MB
    __bf16* hnorm = (__bf16*)alloc((size_t)NTOK * D_MODEL * 2);       //  16-32
    __bf16* wqb   = (__bf16*)alloc((size_t)D_MODEL * D_MODEL * 2);    //  32-40 (wq|wk adjacent = fused QK weight)
    __bf16* wkb   = (__bf16*)alloc((size_t)D_MODEL * D_MODEL * 2);    //  40-48
    __bf16* wvb   = (__bf16*)alloc((size_t)D_MODEL * D_MODEL * 2);    //  48-56
    __bf16* wob   = (__bf16*)alloc((size_t)D_MODEL * D_MODEL * 2);    //  56-64
    __bf16* w1b   = (__bf16*)alloc((size_t)FF * D_MODEL * 2);         //  64-96
    __bf16* w2b   = (__bf16*)alloc((size_t)D_MODEL * FF * 2);         //  96-128
    __bf16* QKb   = (__bf16*)alloc((size_t)NTOK * 2 * D_MODEL * 2);   // 128-160 (fused [tok][4096])
    __bf16* Vtg   = (__bf16*)alloc((size_t)NTOK * D_MODEL * 2);       // 160-176 V^T [b,h,d,s]
    __bf16* Ab    = (__bf16*)alloc((size_t)NTOK * D_MODEL * 2);       // 176-192
    float*  x2    = (float*)alloc((size_t)NTOK * D_MODEL * 4);        // 192-224 f32
    __bf16* gb    = QKb;              // FFN intermediate (64 MB) aliases QKb+Vtg+Ab (dead post O-proj)
    float*  p0    = (float*)(ws);     // W2 split-K partials: slice0 @ 0-32MB, slice1 @ 32-64MB
    float*  p1    = p0 + (size_t)NTOK * D_MODEL;   // = ws + 32MB (aliases tokb..wob, dead by W2)

    // fused converts: (8+4*4+16+16)M elems / 1024 per block
    cvt_all<<<56 * 1024, 256, 0, stream>>>(tok, Wq, Wk, Wv, Wo, W1, W2,
                                           tokb, wqb, wkb, wvb, wob, w1b, w2b);

    ln_bf16<<<NTOK, 256, 0, stream>>>(x, ln1w, ln1b, hnorm);

    // fused Q+K projection: N=4096 -> 256 blocks (full GPU)
    const int g_qk = (NTOK / 256) * ((2 * D_MODEL) / 256);  // 256
    gemm_bt8<0, 1><<<g_qk, 512, 0, stream>>>(hnorm, wqb, QKb, nullptr, nullptr,
                                             NTOK, 2 * D_MODEL, D_MODEL);
    const int g_sq = (NTOK / 256) * (D_MODEL / 256);        // 128
    gemm_bt8<3, 1><<<g_sq, 512, 0, stream>>>(tokb, wvb, Vtg, nullptr, nullptr,
                                             NTOK, D_MODEL, D_MODEL);

    attn_causal<<<dim3(SEQ / 128, NHEAD, BATCH), 512, 0, stream>>>(QKb, QKb + D_MODEL, Vtg, Ab);

    gemm_bt8<2, 1><<<g_sq, 512, 0, stream>>>(Ab, wob, nullptr, x2, x, NTOK, D_MODEL, D_MODEL);

    ln_bf16<<<NTOK, 256, 0, stream>>>(x2, ln2w, ln2b, hnorm);   // h2

    const int g_ff = (NTOK / 256) * (FF / 256);             // 512
    gemm_bt8<1, 1><<<g_ff, 512, 0, stream>>>(hnorm, w1b, gb, nullptr, nullptr,
                                             NTOK, FF, D_MODEL);
    // W2 with split-K=2 (K=8192): 256 blocks, f32 partials, then fused reduce+residual
    gemm_bt8<4, 2><<<2 * g_sq, 512, 0, stream>>>(gb, w2b, nullptr, p0, nullptr,
                                                 NTOK, D_MODEL, FF);
    add_reduce<<<(NTOK * D_MODEL) / 1024, 256, 0, stream>>>(p0, p1, x2, out);
}

// Round 8
// 647.685 us; speedup vs baseline: 1.8220x; 1.1146x over previous
//
#include <hip/hip_runtime.h>
#include <hip/hip_bf16.h>
#include <math.h>

#define D_MODEL 2048
#define SEQ     2048
#define BATCH   2
#define NTOK    (BATCH*SEQ)      // 4096
#define NHEAD   16
#define HDIM    128
#define FF      8192

typedef float  f32x4  __attribute__((ext_vector_type(4)));
typedef __bf16 bf16x8 __attribute__((ext_vector_type(8)));

__device__ __forceinline__ unsigned short f2bfbits(float f) {
    unsigned u = __builtin_bit_cast(unsigned, f);
    return (unsigned short)((u + 0x7fffu + ((u >> 16) & 1u)) >> 16);
}
__device__ __forceinline__ __bf16 f2bf(float f) {
    unsigned short h = f2bfbits(f);
    return __builtin_bit_cast(__bf16, h);
}

__device__ __forceinline__ void gld_lds16(const void* g, void* l) {
    __builtin_amdgcn_global_load_lds(
        (const __attribute__((address_space(1))) unsigned int*)g,
        (__attribute__((address_space(3))) unsigned int*)l, 16, 0, 0);
}

// ---------------- fused f32 -> bf16 convert for tok + all 6 weights -------------
__global__ __launch_bounds__(256) void cvt_all(
        const float* __restrict__ tok, const float* __restrict__ wq,
        const float* __restrict__ wk,  const float* __restrict__ wv,
        const float* __restrict__ wo,  const float* __restrict__ w1,
        const float* __restrict__ w2,
        __bf16* __restrict__ tokb, __bf16* __restrict__ wqb,
        __bf16* __restrict__ wkb,  __bf16* __restrict__ wvb,
        __bf16* __restrict__ wob,  __bf16* __restrict__ w1b,
        __bf16* __restrict__ w2b) {
    const size_t M4 = 4u * 1024 * 1024;
    size_t i = (size_t)blockIdx.x * 1024 + (size_t)threadIdx.x * 4;
    const float* src; __bf16* dst; size_t off;
    if      (i < 2*M4)  { src = tok; dst = tokb; off = i; }
    else if (i < 3*M4)  { src = wq;  dst = wqb;  off = i - 2*M4; }
    else if (i < 4*M4)  { src = wk;  dst = wkb;  off = i - 3*M4; }
    else if (i < 5*M4)  { src = wv;  dst = wvb;  off = i - 4*M4; }
    else if (i < 6*M4)  { src = wo;  dst = wob;  off = i - 5*M4; }
    else if (i < 10*M4) { src = w1;  dst = w1b;  off = i - 6*M4; }
    else                { src = w2;  dst = w2b;  off = i - 10*M4; }
    float4 v = *(const float4*)(src + off);
    ushort4 o;
    o.x = f2bfbits(v.x); o.y = f2bfbits(v.y);
    o.z = f2bfbits(v.z); o.w = f2bfbits(v.w);
    *(ushort4*)((unsigned short*)dst + off) = o;
}

// ---------------- split-K reduce: out = p0 + p1 + resid (f32) ----------------
__global__ __launch_bounds__(256) void add_reduce(
        const float* __restrict__ p0, const float* __restrict__ p1,
        const float* __restrict__ resid, float* __restrict__ out) {
    int i = blockIdx.x * 256 + threadIdx.x;
    float4 a = ((const float4*)p0)[i];
    float4 b = ((const float4*)p1)[i];
    float4 r = ((const float4*)resid)[i];
    float4 o;
    o.x = a.x + b.x + r.x; o.y = a.y + b.y + r.y;
    o.z = a.z + b.z + r.z; o.w = a.w + b.w + r.w;
    ((float4*)out)[i] = o;
}

// ---------------- LayerNorm: f32 in -> bf16 out, one block per row ----------------
__global__ __launch_bounds__(256) void ln_bf16(
        const float* __restrict__ x, const float* __restrict__ w,
        const float* __restrict__ b, __bf16* __restrict__ out) {
    const int row = blockIdx.x;
    const int tid = threadIdx.x;
    const float* xr = x + (size_t)row * D_MODEL;
    float4 v0 = *(const float4*)(xr + tid * 8);
    float4 v1 = *(const float4*)(xr + tid * 8 + 4);
    float va[8] = {v0.x, v0.y, v0.z, v0.w, v1.x, v1.y, v1.z, v1.w};
    float s = 0.f, ss = 0.f;
#pragma unroll
    for (int j = 0; j < 8; ++j) { s += va[j]; ss += va[j] * va[j]; }
#pragma unroll
    for (int m = 32; m; m >>= 1) { s += __shfl_xor(s, m, 64); ss += __shfl_xor(ss, m, 64); }
    __shared__ float red[8];
    const int wid = tid >> 6;
    if ((tid & 63) == 0) { red[wid * 2] = s; red[wid * 2 + 1] = ss; }
    __syncthreads();
    s  = red[0] + red[2] + red[4] + red[6];
    ss = red[1] + red[3] + red[5] + red[7];
    const float mu   = s * (1.0f / D_MODEL);
    const float var  = ss * (1.0f / D_MODEL) - mu * mu;
    const float rstd = rsqrtf(var + 1e-5f);
    const int c = tid * 8;
    ushort4 o0, o1;
    unsigned short ob[8];
#pragma unroll
    for (int j = 0; j < 8; ++j)
        ob[j] = f2bfbits((va[j] - mu) * rstd * w[c + j] + b[c + j]);
    o0.x = ob[0]; o0.y = ob[1]; o0.z = ob[2]; o0.w = ob[3];
    o1.x = ob[4]; o1.y = ob[5]; o1.z = ob[6]; o1.w = ob[7];
    ushort4* op = (ushort4*)(out + (size_t)row * D_MODEL + c);
    op[0] = o0; op[1] = o1;
}

// ================== GEMM core (device) ==================
// C[M,N] = A[M,K] @ B[N,K]^T, 512 threads = 8 waves.
// GEO=0: 256x256 tile, waves 2Mx4N own 128x64, acc[8][4]; 4-phase/K-tile,
//        2 LDS buffers (128KB), 1-tile-deep prefetch, vmcnt(0) at P4 end.
// GEO=1: 128x256 tile, waves 2Mx4N own 64x64, acc[4][4]; 1 phase/K-tile,
//        3 LDS buffers (144KB), 2-tile-deep prefetch, counted vmcnt(6).
// Swizzle both-sides (rule #21): 16B-chunk col X ^= (r&7)<<4 -> 2-way = free.
// vmcnt ALWAYS before s_barrier (own-loads-landed + all-arrived => globally landed).
// EPI: 0 bf16 | 1 GELU bf16 | 2 f32+resid | 3 bf16 transposed [b,h,hd,s] | 4 f32 partial

template <int EPI, int MM>
__device__ __forceinline__ void gemm_epi(
        f32x4 (*acc)[4], int BMsz, int WMsz,
        int bm, int bn, int wm, int wn, int lhi, int l16,
        int M, int N, int slice,
        __bf16* __restrict__ Cb, float* __restrict__ Cf,
        const float* __restrict__ resid) {
#pragma unroll
    for (int m = 0; m < MM; ++m) {
        const int row = bm * BMsz + wm * WMsz + m * 16 + lhi * 4;
#pragma unroll
        for (int n = 0; n < 4; ++n) {
            const int col = bn * 256 + wn * 64 + n * 16 + l16;
            if (EPI == 3) {
                const int h = col >> 7, hd = col & 127;
                const size_t obase =
                    ((((size_t)(row >> 11) * NHEAD + h) * HDIM + hd) << 11) + (row & 2047);
                ushort4 o;
                o.x = f2bfbits(acc[m][n][0]); o.y = f2bfbits(acc[m][n][1]);
                o.z = f2bfbits(acc[m][n][2]); o.w = f2bfbits(acc[m][n][3]);
                *(ushort4*)((unsigned short*)Cb + obase) = o;
            } else {
#pragma unroll
                for (int r = 0; r < 4; ++r) {
                    float v = acc[m][n][r];
                    size_t off = (size_t)(row + r) * N + col;
                    if (EPI == 0) {
                        Cb[off] = f2bf(v);
                    } else if (EPI == 1) {
                        Cb[off] = f2bf(0.5f * v * (1.0f + erff(v * 0.70710678118654752f)));
                    } else if (EPI == 2) {
                        Cf[off] = v + resid[off];
                    } else {  // EPI == 4
                        Cf[(size_t)slice * M * N + off] = v;
                    }
                }
            }
        }
    }
}

template <int EPI, int SPLITK, int GEO>
__device__ __forceinline__ void gemm_core(
        const __bf16* __restrict__ A, const __bf16* __restrict__ Bm,
        __bf16* __restrict__ Cb, float* __restrict__ Cf,
        const float* __restrict__ resid, int M, int N, int K,
        int bm, int bn, int slice, char* smem) {
    const int tid = threadIdx.x;
    const int wid = tid >> 6, lane = tid & 63;
    const int l16 = lane & 15, lhi = lane >> 4;
    const int wm = wid >> 2, wn = wid & 3;
    const int tps = (K >> 6) / SPLITK;
    const int t0 = slice * tps, t1 = t0 + tps;

    // stage 128 rows x 64 cols (16KB): inverse-swizzled source, linear LDS dest
    auto stage128 = [&](char* dst, const __bf16* G, int kt, int rowOff) {
#pragma unroll
        for (int j = 0; j < 2; ++j) {
            int idx = j * 512 + tid;            // 0..1023 chunks
            int r = idx >> 3;                   // 0..127
            int Xc = (idx & 7) << 4;
            int Xs = Xc ^ ((r & 7) << 4);
            gld_lds16((const char*)(G + ((size_t)(rowOff + r) * K + kt * 64)) + Xs,
                      dst + idx * 16);
        }
    };

    if constexpr (GEO == 0) {
        const __bf16* Ag = A  + (size_t)bm * 256 * K;
        const __bf16* Bg = Bm + (size_t)bn * 256 * K;
        f32x4 acc[8][4] = {};
        bf16x8 af0[4][2], af1[4][2], bq0[2][2], bq1[2][2];
        const char *Ab_, *Bb_;
        auto ldA = [&](bf16x8 (&dst)[4][2], int qm) {
#pragma unroll
            for (int i = 0; i < 4; ++i)
#pragma unroll
                for (int ks = 0; ks < 2; ++ks) {
                    int r = wm * 128 + (qm * 4 + i) * 16 + l16;
                    int X = ks * 64 + lhi * 16;
                    dst[i][ks] = *(const bf16x8*)(Ab_ + r * 128 + (X ^ ((r & 7) << 4)));
                }
        };
        auto ldB = [&](bf16x8 (&dst)[2][2], int qn) {
#pragma unroll
            for (int j = 0; j < 2; ++j)
#pragma unroll
                for (int ks = 0; ks < 2; ++ks) {
                    int r = wn * 64 + (qn * 2 + j) * 16 + l16;
                    int X = ks * 64 + lhi * 16;
                    dst[j][ks] = *(const bf16x8*)(Bb_ + r * 128 + (X ^ ((r & 7) << 4)));
                }
        };
        auto mfmaQ = [&](bf16x8 (&a)[4][2], bf16x8 (&b)[2][2], int mo, int no) {
            __builtin_amdgcn_s_setprio(1);
#pragma unroll
            for (int i = 0; i < 4; ++i)
#pragma unroll
                for (int j = 0; j < 2; ++j)
#pragma unroll
                    for (int ks = 0; ks < 2; ++ks)
                        acc[mo + i][no + j] = __builtin_amdgcn_mfma_f32_16x16x32_bf16(
                            a[i][ks], b[j][ks], acc[mo + i][no + j], 0, 0, 0);
            __builtin_amdgcn_s_setprio(0);
        };
        auto stageT = [&](int t, int c) {
            char* base = smem + c * 65536;
            stage128(base,         Ag, t, 0);
            stage128(base + 16384, Ag, t, 128);
            stage128(base + 32768, Bg, t, 0);
            stage128(base + 49152, Bg, t, 128);
        };

        stageT(t0, 0);
        asm volatile("s_waitcnt vmcnt(0)" ::: "memory");
        __builtin_amdgcn_s_barrier();

        for (int t = t0; t < t1; ++t) {
            const int cur = (t - t0) & 1;
            Ab_ = smem + cur * 65536;
            Bb_ = Ab_ + 32768;
            const bool pf = (t + 1 < t1);
            // P1: issue ALL of tile t+1's staging (max wait distance)
            if (pf) stageT(t + 1, cur ^ 1);
            ldA(af0, 0); ldB(bq0, 0);
            __builtin_amdgcn_s_barrier();
            asm volatile("s_waitcnt lgkmcnt(0)" ::: "memory");
            __builtin_amdgcn_sched_barrier(0);
            mfmaQ(af0, bq0, 0, 0);
            __builtin_amdgcn_s_barrier();
            // P2
            ldB(bq1, 1);
            __builtin_amdgcn_s_barrier();
            asm volatile("s_waitcnt lgkmcnt(0)" ::: "memory");
            __builtin_amdgcn_sched_barrier(0);
            mfmaQ(af0, bq1, 0, 2);
            __builtin_amdgcn_s_barrier();
            // P3
            ldA(af1, 1);
            __builtin_amdgcn_s_barrier();
            asm volatile("s_waitcnt lgkmcnt(0)" ::: "memory");
            __builtin_amdgcn_sched_barrier(0);
            mfmaQ(af1, bq0, 4, 0);
            __builtin_amdgcn_s_barrier();
            // P4: register-only MFMA, then drain (loads issued 3 phases ago)
            mfmaQ(af1, bq1, 4, 2);
            if (pf) asm volatile("s_waitcnt vmcnt(0)" ::: "memory");
            __builtin_amdgcn_s_barrier();
        }
        gemm_epi<EPI, 8>(acc, 256, 128, bm, bn, wm, wn, lhi, l16,
                         M, N, slice, Cb, Cf, resid);
    } else {
        // GEO1: 128x256 tile, 3 buffers (48KB each), 2-tile-deep, counted vmcnt(6)
        const __bf16* Ag = A  + (size_t)bm * 128 * K;
        const __bf16* Bg = Bm + (size_t)bn * 256 * K;
        f32x4 acc[4][4] = {};
        auto stageT = [&](int t, int c) {
            char* base = smem + c * 49152;
            stage128(base,         Ag, t, 0);      // A: 128x64 = 16KB
            stage128(base + 16384, Bg, t, 0);      // B: 256x64 = 32KB
            stage128(base + 32768, Bg, t, 128);
        };
        stageT(t0, 0);
        if (t0 + 1 < t1) {
            stageT(t0 + 1, 1);
            asm volatile("s_waitcnt vmcnt(6)" ::: "memory");  // t0 landed
        } else {
            asm volatile("s_waitcnt vmcnt(0)" ::: "memory");
        }
        __builtin_amdgcn_s_barrier();

        for (int t = t0; t < t1; ++t) {
            const int c = (t - t0) % 3;
            if (t + 2 < t1) stageT(t + 2, (c + 2) % 3);   // that buf died at t-1's end barrier
            const char* Ab_ = smem + c * 49152;
            const char* Bb_ = Ab_ + 16384;
            bf16x8 af[4][2], bq[4][2];
#pragma unroll
            for (int i = 0; i < 4; ++i)
#pragma unroll
                for (int ks = 0; ks < 2; ++ks) {
                    int r = wm * 64 + i * 16 + l16;
                    int X = ks * 64 + lhi * 16;
                    af[i][ks] = *(const bf16x8*)(Ab_ + r * 128 + (X ^ ((r & 7) << 4)));
                }
#pragma unroll
            for (int j = 0; j < 4; ++j)
#pragma unroll
                for (int ks = 0; ks < 2; ++ks) {
                    int r = wn * 64 + j * 16 + l16;
                    int X = ks * 64 + lhi * 16;
                    bq[j][ks] = *(const bf16x8*)(Bb_ + r * 128 + (X ^ ((r & 7) << 4)));
                }
            asm volatile("s_waitcnt lgkmcnt(0)" ::: "memory");
            __builtin_amdgcn_sched_barrier(0);
            __builtin_amdgcn_s_setprio(1);
#pragma unroll
            for (int i = 0; i < 4; ++i)
#pragma unroll
                for (int j = 0; j < 4; ++j)
#pragma unroll
                    for (int ks = 0; ks < 2; ++ks)
                        acc[i][j] = __builtin_amdgcn_mfma_f32_16x16x32_bf16(
                            af[i][ks], bq[j][ks], acc[i][j], 0, 0, 0);
            __builtin_amdgcn_s_setprio(0);
            // gate t+1's buffer: counted vmcnt BEFORE barrier (sound: own-landed + all-arrived)
            if (t + 2 < t1) {
                asm volatile("s_waitcnt vmcnt(6)" ::: "memory");   // t+1 landed, t+2 flying
                __builtin_amdgcn_s_barrier();
            } else if (t + 1 < t1) {
                asm volatile("s_waitcnt vmcnt(0)" ::: "memory");
                __builtin_amdgcn_s_barrier();
            }
        }
        gemm_epi<EPI, 4>(acc, 128, 64, bm, bn, wm, wn, lhi, l16,
                         M, N, slice, Cb, Cf, resid);
    }
}

// MAP: 0 = generic XCD round-robin swizzle; 1 = bn-stripes of 4 per XCD (bm-major
// within, A-panel + 4MB B resident — FFN1); 2 = bm-stripes of 4 per XCD (O-proj).
template <int EPI, int SPLITK, int GEO, int MAP>
__global__ __launch_bounds__(512, 2) void gemm_k(
        const __bf16* __restrict__ A, const __bf16* __restrict__ Bm,
        __bf16* __restrict__ Cb, float* __restrict__ Cf,
        const float* __restrict__ resid, int M, int N, int K) {
    __shared__ __align__(16) char smem[GEO ? 147456 : 131072];
    int bm, bn, slice = 0;
    if (MAP == 0) {
        int id = blockIdx.x;
        const int cpx = gridDim.x >> 3;
        id = (id & 7) * cpx + (id >> 3);
        const int nbn = N >> 8;
        if (SPLITK == 2) {
            const int nblk = (M >> (GEO ? 7 : 8)) * nbn;
            slice = id / nblk;
            id -= slice * nblk;
        }
        bm = id / nbn; bn = id % nbn;
    } else if (MAP == 1) {
        const int x = blockIdx.x & 7, j = blockIdx.x >> 3;
        bn = (x << 2) | (j & 3); bm = j >> 2;
    } else {
        const int x = blockIdx.x & 7, j = blockIdx.x >> 3;
        bm = (x << 2) | (j & 3); bn = j >> 2;
    }
    gemm_core<EPI, SPLITK, GEO>(A, Bm, Cb, Cf, resid, M, N, K, bm, bn, slice, smem);
}

// Grouped QK + V projection: 512 blocks. Per XCD x: j<32 -> QK tile (256x256,
// A-panels + B-panel resident), j>=32 -> V tile (128x256, EPI=3 transposed out).
__global__ __launch_bounds__(512, 2) void gemm_qkv(
        const __bf16* __restrict__ hn, const __bf16* __restrict__ wqk,
        __bf16* __restrict__ QKb, const __bf16* __restrict__ tokb,
        const __bf16* __restrict__ wv, __bf16* __restrict__ Vtg) {
    __shared__ __align__(16) char smem[147456];
    const int x = blockIdx.x & 7, j = blockIdx.x >> 3;   // x = XCD, j = 0..63
    if (j < 32) {
        const int bm = ((x >> 1) << 2) | (j & 3);        // 0..15
        const int bn = ((x & 1) << 3) | (j >> 2);        // 0..15
        gemm_core<0, 1, 0>(hn, wqk, QKb, nullptr, nullptr,
                           NTOK, 2 * D_MODEL, D_MODEL, bm, bn, 0, smem);
    } else {
        const int jv = j - 32;
        const int bm = ((x >> 1) << 3) | (jv & 7);       // 0..31
        const int bn = ((x & 1) << 2) | (jv >> 3);       // 0..7
        gemm_core<3, 1, 1>(tokb, wv, Vtg, nullptr, nullptr,
                           NTOK, D_MODEL, D_MODEL, bm, bn, 0, smem);
    }
}

// ---------------- Causal flash attention (8 waves, QBLK=128, pipelined) ----------
#define LDQK 4096
__global__ __launch_bounds__(512) void attn_causal(
        const __bf16* __restrict__ Q, const __bf16* __restrict__ K,
        const __bf16* __restrict__ Vt, __bf16* __restrict__ O) {
    const int qt = gridDim.x - 1 - blockIdx.x;
    const int h = blockIdx.y, bb = blockIdx.z;
    const int tid = threadIdx.x, wid = tid >> 6, lane = tid & 63;
    const int l16 = lane & 15, lhi = lane >> 4;
    __shared__ __align__(16) __bf16 Ks[2][64 * 128];
    __shared__ __align__(16) __bf16 Vs[128 * 64];
    __shared__ __align__(16) __bf16 Pl[8][16 * 72];

    const size_t qkbase = ((size_t)bb * SEQ) * LDQK + (size_t)h * HDIM;
    const size_t obase  = ((size_t)bb * SEQ) * D_MODEL + (size_t)h * HDIM;
    const size_t vtbase = (((size_t)bb * NHEAD + h) * HDIM) << 11;
    const int q0 = qt * 128 + wid * 16;

    bf16x8 qf[4];
#pragma unroll
    for (int ks = 0; ks < 4; ++ks)
        qf[ks] = *(const bf16x8*)(Q + qkbase + (size_t)(q0 + l16) * LDQK + ks * 32 + lhi * 8);

    auto stageK = [&](int kt, int buf) {
#pragma unroll
        for (int j = 0; j < 2; ++j) {
            int idx = j * 512 + tid;
            int row = idx >> 4, c8 = idx & 15;
            int c8s = c8 ^ (row & 7);
            gld_lds16(K + qkbase + (size_t)(kt * 64 + row) * LDQK + c8s * 8,
                      &Ks[buf][0] + idx * 8);
        }
    };
    auto stageV = [&](int kt) {
#pragma unroll
        for (int j = 0; j < 2; ++j) {
            int idx = j * 512 + tid;
            int row = idx >> 3, c8 = idx & 7;
            int c8s = c8 ^ (row & 7);
            gld_lds16(Vt + vtbase + (size_t)row * SEQ + kt * 64 + c8s * 8, Vs + idx * 8);
        }
    };

    f32x4 accO[8] = {};
    float m_run[4], l_run[4];
#pragma unroll
    for (int r = 0; r < 4; ++r) { m_run[r] = -1e30f; l_run[r] = 0.f; }

    const float scale2 = 0.08838834764831845f * 1.4426950408889634f;
    const int NKT = (qt + 1) * 2;

    stageK(0, 0);
    asm volatile("s_waitcnt vmcnt(0)" ::: "memory");
    __builtin_amdgcn_s_barrier();
    __builtin_amdgcn_sched_barrier(0);

    for (int kt = 0; kt < NKT; ++kt) {
        const int cb = kt & 1;
        const bool pf = (kt + 1 < NKT);
        stageV(kt);
        if (pf) stageK(kt + 1, cb ^ 1);

        f32x4 s[4] = {};
        __builtin_amdgcn_s_setprio(1);
#pragma unroll
        for (int nb = 0; nb < 4; ++nb) {
            const int tok = nb * 16 + l16;
#pragma unroll
            for (int ks = 0; ks < 4; ++ks) {
                int co = (ks * 64 + lhi * 16) ^ ((tok & 7) << 4);
                bf16x8 kf = *(const bf16x8*)((const char*)&Ks[cb][0] + tok * 256 + co);
                s[nb] = __builtin_amdgcn_mfma_f32_16x16x32_bf16(qf[ks], kf, s[nb], 0, 0, 0);
            }
        }
        __builtin_amdgcn_s_setprio(0);

        if (((kt + 1) << 6) > q0) {
#pragma unroll
            for (int nb = 0; nb < 4; ++nb)
#pragma unroll
                for (int r = 0; r < 4; ++r) {
                    float sv = s[nb][r] * scale2;
                    if ((kt * 64 + nb * 16 + l16) > (q0 + lhi * 4 + r)) sv = -1e30f;
                    s[nb][r] = sv;
                }
        } else {
#pragma unroll
            for (int nb = 0; nb < 4; ++nb)
#pragma unroll
                for (int r = 0; r < 4; ++r) s[nb][r] *= scale2;
        }

        float alpha[4];
#pragma unroll
        for (int r = 0; r < 4; ++r) {
            float mx = fmaxf(fmaxf(s[0][r], s[1][r]), fmaxf(s[2][r], s[3][r]));
#pragma unroll
            for (int m = 8; m; m >>= 1) mx = fmaxf(mx, __shfl_xor(mx, m, 64));
            float mnew = fmaxf(m_run[r], mx);
            alpha[r] = exp2f(m_run[r] - mnew);
            float rs = 0.f;
#pragma unroll
            for (int nb = 0; nb < 4; ++nb) {
                float p = exp2f(s[nb][r] - mnew);
                s[nb][r] = p;
                rs += p;
            }
#pragma unroll
            for (int m = 8; m; m >>= 1) rs += __shfl_xor(rs, m, 64);
            l_run[r] = l_run[r] * alpha[r] + rs;
            m_run[r] = mnew;
        }
#pragma unroll
        for (int d8 = 0; d8 < 8; ++d8)
#pragma unroll
            for (int r = 0; r < 4; ++r) accO[d8][r] *= alpha[r];
#pragma unroll
        for (int nb = 0; nb < 4; ++nb)
#pragma unroll
            for (int r = 0; r < 4; ++r)
                Pl[wid][(lhi * 4 + r) * 72 + nb * 16 + l16] = f2bf(s[nb][r]);

        if (pf) asm volatile("s_waitcnt vmcnt(2)" ::: "memory");
        else    asm volatile("s_waitcnt vmcnt(0)" ::: "memory");
        __builtin_amdgcn_s_barrier();
        __builtin_amdgcn_sched_barrier(0);

        __builtin_amdgcn_s_setprio(1);
#pragma unroll
        for (int ks2 = 0; ks2 < 2; ++ks2) {
            bf16x8 pa = *(const bf16x8*)(&Pl[wid][l16 * 72 + ks2 * 32 + lhi * 8]);
#pragma unroll
            for (int d8 = 0; d8 < 8; ++d8) {
                const int d = d8 * 16 + l16;
                const int co = ((ks2 * 4 + lhi) ^ (d & 7)) << 4;
                bf16x8 vf = *(const bf16x8*)((const char*)Vs + d * 128 + co);
                accO[d8] = __builtin_amdgcn_mfma_f32_16x16x32_bf16(pa, vf, accO[d8], 0, 0, 0);
            }
        }
        __builtin_amdgcn_s_setprio(0);

        asm volatile("s_waitcnt vmcnt(0)" ::: "memory");
        __builtin_amdgcn_s_barrier();
        __builtin_amdgcn_sched_barrier(0);
    }

#pragma unroll
    for (int d8 = 0; d8 < 8; ++d8)
#pragma unroll
        for (int r = 0; r < 4; ++r) {
            float o = accO[d8][r] / l_run[r];
            O[obase + (size_t)(q0 + lhi * 4 + r) * D_MODEL + d8 * 16 + l16] = f2bf(o);
        }
}

// ---------------- host launcher ----------------
extern "C" void kernel_launch(void* const* d_in, const int* in_sizes, int n_in,
                              void* d_out, int out_size, void* d_ws, size_t ws_size,
                              hipStream_t stream) {
    const float* x    = (const float*)d_in[0];
    const float* tok  = (const float*)d_in[1];
    const float* Wq   = (const float*)d_in[2];
    const float* Wk   = (const float*)d_in[3];
    const float* Wv   = (const float*)d_in[4];
    const float* Wo   = (const float*)d_in[5];
    const float* W1   = (const float*)d_in[6];
    const float* W2   = (const float*)d_in[7];
    const float* ln1w = (const float*)d_in[8];
    const float* ln1b = (const float*)d_in[9];
    const float* ln2w = (const float*)d_in[10];
    const float* ln2b = (const float*)d_in[11];
    float* out = (float*)d_out;

    char* ws = (char*)d_ws;
    size_t off = 0;
    auto alloc = [&](size_t bytes) { void* p = ws + off; off += bytes; return p; };
    __bf16* tokb  = (__bf16*)alloc((size_t)NTOK * D_MODEL * 2);       //   0-16 MB
    __bf16* hnorm = (__bf16*)alloc((size_t)NTOK * D_MODEL * 2);       //  16-32
    __bf16* wqb   = (__bf16*)alloc((size_t)D_MODEL * D_MODEL * 2);    //  32-40 (wq|wk adjacent)
    __bf16* wkb   = (__bf16*)alloc((size_t)D_MODEL * D_MODEL * 2);    //  40-48
    __bf16* wvb   = (__bf16*)alloc((size_t)D_MODEL * D_MODEL * 2);    //  48-56
    __bf16* wob   = (__bf16*)alloc((size_t)D_MODEL * D_MODEL * 2);    //  56-64
    __bf16* w1b   = (__bf16*)alloc((size_t)FF * D_MODEL * 2);         //  64-96
    __bf16* w2b   = (__bf16*)alloc((size_t)D_MODEL * FF * 2);         //  96-128
    __bf16* QKb   = (__bf16*)alloc((size_t)NTOK * 2 * D_MODEL * 2);   // 128-160
    __bf16* Vtg   = (__bf16*)alloc((size_t)NTOK * D_MODEL * 2);       // 160-176
    __bf16* Ab    = (__bf16*)alloc((size_t)NTOK * D_MODEL * 2);       // 176-192
    float*  x2    = (float*)alloc((size_t)NTOK * D_MODEL * 4);        // 192-224 f32
    __bf16* gb    = QKb;              // FFN intermediate aliases QKb.. (dead post O-proj)
    float*  p0    = (float*)(ws);     // W2 split-K partials: 0-32MB / 32-64MB
    float*  p1    = p0 + (size_t)NTOK * D_MODEL;

    cvt_all<<<56 * 1024, 256, 0, stream>>>(tok, Wq, Wk, Wv, Wo, W1, W2,
                                           tokb, wqb, wkb, wvb, wob, w1b, w2b);

    ln_bf16<<<NTOK, 256, 0, stream>>>(x, ln1w, ln1b, hnorm);

    // grouped QK (256 tiles) + V (256 small tiles) = 512 blocks, 2 full rounds
    gemm_qkv<<<512, 512, 0, stream>>>(hnorm, wqb, QKb, tokb, wvb, Vtg);

    attn_causal<<<dim3(SEQ / 128, NHEAD, BATCH), 512, 0, stream>>>(QKb, QKb + D_MODEL, Vtg, Ab);

    // O-proj: GEO1 (128x256) -> 256 blocks, full GPU; MAP=2 bm-stripes per XCD
    gemm_k<2, 1, 1, 2><<<256, 512, 0, stream>>>(Ab, wob, nullptr, x2, x,
                                                NTOK, D_MODEL, D_MODEL);

    ln_bf16<<<NTOK, 256, 0, stream>>>(x2, ln2w, ln2b, hnorm);

    // FFN1: MAP=1 bn-stripes of 4 per XCD (A-panel resident, B 4MB resident)
    gemm_k<1, 1, 0, 1><<<512, 512, 0, stream>>>(hnorm, w1b, gb, nullptr, nullptr,
                                                NTOK, FF, D_MODEL);
    // W2 split-K=2: 256 blocks, f32 partials + fused reduce+residual
    gemm_k<4, 2, 0, 0><<<256, 512, 0, stream>>>(gb, w2b, nullptr, p0, nullptr,
                                                NTOK, D_MODEL, FF);
    add_reduce<<<(NTOK * D_MODEL) / 1024, 256, 0, stream>>>(p0, p1, x2, out);
}